// Round 2
// 2903.855 us; speedup vs baseline: 1.2680x; 1.2680x over previous
//
#include <hip/hip_runtime.h>
#include <hip/hip_bf16.h>

// LinearformerBlock on MI355X (gfx950). I/O is FP32 (per reference dtypes);
// internals bf16 MFMA with fp32 accumulation. B=4,N=4096,D=1024,H=4,DH=256,FF=4096.
//
// ws = 30,670,848 B (~29.3 MiB) — EXACTLY the footprint of the proven baseline
// (r5's +4MB P buffer is suspected of overflowing ws -> container death; this
// version reverts to the exact original allocation total).
//
// d_out (64MB fp32) doubles as scratch: first half = xb (bf16 cast of x),
// second half = x2 (bf16). Final dense writes fp32 rows forward-order.
// Clobber analysis: out chunk R writes rows [1024R,1024R+1024) = bytes
// [4MB*R, 4MB*R+4MB), clobbering x2 rows [2048R-16384, 2048R-14336). For
// chunks > R this stays below their first needed row 1024(R+1) for all R.
// Within chunk R the only self-conflict is R=15: its out-write covers x2 rows
// [14336,16384) which its own x2@wd term reads ([15360,16384)) — an
// intra-kernel read/write race. Fix: copy those 1024 rows to XS (2MB, the old
// X3 slot) right before chunk 15 and point its x2-term at XS.
//
// r6 (this round): FFN algebra change — out = x2@wd + g@(wff2@wd) + (b2@wd+bd).
// Precompute WCD = wff2@wd once (bf16 [1024n][4096k] BT-form, lands in S2,
// REPLACING wff2T) and OB = b2@wd + bd (4KB, overlaid on dead CTX). Per chunk:
// bias_bcast seeds out_R = OB; split-K atomic GEMMs accumulate g_R@WCD
// (z=8 -> 512 blocks) and x2_R@wd (z=4 -> 256 blocks). This removes the
// 64-block 88.7us gemm2/gemm3 launches (2.7% occupancy, ~1.9ms total) without
// any workspace growth, and x3 never rounds through bf16.

typedef __hip_bfloat16 bf16;
typedef __attribute__((ext_vector_type(8))) short short8;
typedef __attribute__((ext_vector_type(4))) float floatx4;

__device__ __forceinline__ float b2f(bf16 x) { return __bfloat162float(x); }
__device__ __forceinline__ bf16 f2b(float x) { return __float2bfloat16(x); }
__device__ __forceinline__ float s2f(short s) {
  unsigned int u = ((unsigned int)(unsigned short)s) << 16;
  return __uint_as_float(u);
}
__device__ __forceinline__ short f2s(float f) {
  bf16 h = __float2bfloat16(f);
  return *reinterpret_cast<short*>(&h);
}
__device__ __forceinline__ float gelu_f(float x) {
  float u = 0.7978845608028654f * (x + 0.044715f * x * x * x);
  return 0.5f * x * (1.0f + tanhf(u));
}

// ---------------------------------------------------------------------------
// GEMM: C[m][n] = sum_k A'[m][k] * BT[n][k]   (A' = LN(A) if stats!=null)
// 128x128 tile, BK=32, 4 waves x (4x4) 16x16x32 bf16 MFMA.
// AFP32: A operand is fp32 (LN applied in fp32, packed to bf16 for LDS).
// CFP32: store C as fp32. TRANSC: write C transposed (bf16 only).
// ATOM: epilogue is atomicAdd into fp32 C (bias/res/act must be null/0) —
//       used for split-K where blockIdx.z indexes a K-slice via shA/shB.
// BT operand is always bf16. bias/gamma/beta are fp32. res is bf16, may
// alias C (same-thread read-before-write).
// ---------------------------------------------------------------------------
template <int TRANSC, int AFP32, int CFP32, int ATOM>
__global__ __launch_bounds__(256) void gemm_bt(
    const void* __restrict__ Aop, const bf16* __restrict__ BT, void* Cv,
    int K, int lda, int ldb, int ldc, int zshift,
    long saA, long shA, long saB, long shB, long saC, long shC,
    const float* __restrict__ bias, const bf16* res, int act,
    const float2* stats, const float* __restrict__ gamma,
    const float* __restrict__ beta)
{
  int z = blockIdx.z;
  int zb = z >> zshift, zh = z & ((1 << zshift) - 1);
  long offA = (long)zb * saA + (long)zh * shA;
  long offC = (long)zb * saC + (long)zh * shC;
  const float* Af = (const float*)Aop + offA;
  const bf16*  Ab = (const bf16*)Aop + offA;
  BT += (long)zb * saB + (long)zh * shB;
  bf16*  C  = (bf16*)Cv + offC;
  float* Cf = (float*)Cv + offC;
  if (res) res += offC;
  if (stats) stats += offA / lda;

  __shared__ bf16 As[128 * 32];
  __shared__ bf16 Bs[128 * 32];
  __shared__ bf16 TC[TRANSC ? 128 * 136 : 2];

  const int t = threadIdx.x;
  const int w = t >> 6, l = t & 63;
  const int m0 = blockIdx.y * 128, n0 = blockIdx.x * 128;
  const int wm = (w >> 1) * 64, wn = (w & 1) * 64;
  const int lr = l & 15, lq = l >> 4;

  floatx4 acc[4][4] = {};

  const int sr = t >> 2;        // staging row within half-tile (0..63)
  const int sc = (t & 3) * 8;   // staging col (0,8,16,24)
  const int rowA0 = m0 + sr, rowA1 = m0 + 64 + sr;
  const long o0 = (long)rowA0 * lda + sc;
  const long o1 = (long)rowA1 * lda + sc;

  const bf16* Bp0 = BT + (long)(n0 + sr) * ldb + sc;
  const bf16* Bp1 = BT + (long)(n0 + 64 + sr) * ldb + sc;

  float2 st0, st1;
  if (stats) { st0 = stats[rowA0]; st1 = stats[rowA1]; }

  for (int k0 = 0; k0 < K; k0 += 32) {
    short8 ra0, ra1;
    if constexpr (AFP32) {
      float4 a00 = *(const float4*)(Af + o0 + k0);
      float4 a01 = *(const float4*)(Af + o0 + k0 + 4);
      float4 a10 = *(const float4*)(Af + o1 + k0);
      float4 a11 = *(const float4*)(Af + o1 + k0 + 4);
      float v0[8] = {a00.x, a00.y, a00.z, a00.w, a01.x, a01.y, a01.z, a01.w};
      float v1[8] = {a10.x, a10.y, a10.z, a10.w, a11.x, a11.y, a11.z, a11.w};
      if (stats) {
        float4 g0 = *(const float4*)(gamma + k0 + sc);
        float4 g1 = *(const float4*)(gamma + k0 + sc + 4);
        float4 e0 = *(const float4*)(beta + k0 + sc);
        float4 e1 = *(const float4*)(beta + k0 + sc + 4);
        float gv[8] = {g0.x, g0.y, g0.z, g0.w, g1.x, g1.y, g1.z, g1.w};
        float ev[8] = {e0.x, e0.y, e0.z, e0.w, e1.x, e1.y, e1.z, e1.w};
#pragma unroll
        for (int i = 0; i < 8; i++) {
          v0[i] = (v0[i] - st0.x) * st0.y * gv[i] + ev[i];
          v1[i] = (v1[i] - st1.x) * st1.y * gv[i] + ev[i];
        }
      }
#pragma unroll
      for (int i = 0; i < 8; i++) { ra0[i] = f2s(v0[i]); ra1[i] = f2s(v1[i]); }
    } else {
      ra0 = *(const short8*)(Ab + o0 + k0);
      ra1 = *(const short8*)(Ab + o1 + k0);
      if (stats) {
        float4 g0 = *(const float4*)(gamma + k0 + sc);
        float4 g1 = *(const float4*)(gamma + k0 + sc + 4);
        float4 e0 = *(const float4*)(beta + k0 + sc);
        float4 e1 = *(const float4*)(beta + k0 + sc + 4);
        float gv[8] = {g0.x, g0.y, g0.z, g0.w, g1.x, g1.y, g1.z, g1.w};
        float ev[8] = {e0.x, e0.y, e0.z, e0.w, e1.x, e1.y, e1.z, e1.w};
#pragma unroll
        for (int i = 0; i < 8; i++) {
          ra0[i] = f2s((s2f(ra0[i]) - st0.x) * st0.y * gv[i] + ev[i]);
          ra1[i] = f2s((s2f(ra1[i]) - st1.x) * st1.y * gv[i] + ev[i]);
        }
      }
    }
    short8 rb0 = *(const short8*)(Bp0 + k0);
    short8 rb1 = *(const short8*)(Bp1 + k0);
    __syncthreads();  // prev iter's LDS reads done
    *(short8*)&As[t * 8]        = ra0;
    *(short8*)&As[2048 + t * 8] = ra1;
    *(short8*)&Bs[t * 8]        = rb0;
    *(short8*)&Bs[2048 + t * 8] = rb1;
    __syncthreads();
    short8 af[4], bfr[4];
#pragma unroll
    for (int i = 0; i < 4; i++) {
      af[i]  = *(const short8*)&As[(wm + i * 16 + lr) * 32 + lq * 8];
      bfr[i] = *(const short8*)&Bs[(wn + i * 16 + lr) * 32 + lq * 8];
    }
#pragma unroll
    for (int i = 0; i < 4; i++)
#pragma unroll
      for (int j = 0; j < 4; j++)
        acc[i][j] = __builtin_amdgcn_mfma_f32_16x16x32_bf16(af[i], bfr[j], acc[i][j], 0, 0, 0);
  }

  if constexpr (TRANSC) {
    // C/D layout: col(n) = lane&15, row(m) = (lane>>4)*4 + reg.
#pragma unroll
    for (int i = 0; i < 4; i++) {
      int rloc = wm + i * 16 + lq * 4;
#pragma unroll
      for (int j = 0; j < 4; j++) {
        int cloc = wn + j * 16 + lr;
#pragma unroll
        for (int r = 0; r < 4; r++)
          TC[cloc * 136 + rloc + r] = f2b(acc[i][j][r]);
      }
    }
    __syncthreads();
    long base = (long)n0 * ldc + m0;
#pragma unroll
    for (int p = 0; p < 8; p++) {
      int er = (t >> 4) + p * 16;   // local e row (0..127)
      int mc = (t & 15) * 8;        // local m col
      *(short8*)(C + base + (long)er * ldc + mc) = *(const short8*)&TC[er * 136 + mc];
    }
    return;
  }

#pragma unroll
  for (int i = 0; i < 4; i++) {
    int row0 = m0 + wm + i * 16 + lq * 4;
#pragma unroll
    for (int j = 0; j < 4; j++) {
      int col = n0 + wn + j * 16 + lr;
      if constexpr (ATOM) {
#pragma unroll
        for (int r = 0; r < 4; r++) {
          long idx = (long)(row0 + r) * ldc + col;
          atomicAdd(&Cf[idx], acc[i][j][r]);
        }
      } else {
        float bv = bias ? bias[col] : 0.0f;
#pragma unroll
        for (int r = 0; r < 4; r++) {
          float v = acc[i][j][r] + bv;
          long idx = (long)(row0 + r) * ldc + col;
          if (res) v += b2f(res[idx]);
          if (act) v = gelu_f(v);
          if constexpr (CFP32) Cf[idx] = v; else C[idx] = f2b(v);
        }
      }
    }
  }
}

// ---------------------------------------------------------------------------
// Tiled transpose fp32 -> bf16: dst[c][r] = (bf16)src[r][c].
// Grid: (Csrc/32, Rsrc/32). Block (32,8).
// ---------------------------------------------------------------------------
__global__ void transpose_f2b(const float* __restrict__ src, bf16* __restrict__ dst,
                              int lsrc, int ldst)
{
  __shared__ bf16 tile[32][33];
  int tx = threadIdx.x, ty = threadIdx.y;
  int c0 = blockIdx.x * 32, r0 = blockIdx.y * 32;
#pragma unroll
  for (int j = 0; j < 4; j++)
    tile[ty + j * 8][tx] = f2b(src[(long)(r0 + ty + j * 8) * lsrc + c0 + tx]);
  __syncthreads();
#pragma unroll
  for (int j = 0; j < 4; j++)
    dst[(long)(c0 + ty + j * 8) * ldst + r0 + tx] = tile[tx][ty + j * 8];
}

// convert fp32 -> bf16, 8 elems/thread.
__global__ __launch_bounds__(256) void cvt_f2b(const float* __restrict__ s,
                                               bf16* __restrict__ d)
{
  long i = ((long)blockIdx.x * 256 + threadIdx.x) * 8;
  float4 a = *(const float4*)(s + i);
  float4 b = *(const float4*)(s + i + 4);
  short8 o;
  o[0] = f2s(a.x); o[1] = f2s(a.y); o[2] = f2s(a.z); o[3] = f2s(a.w);
  o[4] = f2s(b.x); o[5] = f2s(b.y); o[6] = f2s(b.z); o[7] = f2s(b.w);
  *(short8*)(d + i) = o;
}

// plain 16B copy (used for the x2 tail rescue before chunk 15).
__global__ __launch_bounds__(256) void copy16(const float4* __restrict__ s,
                                              float4* __restrict__ d)
{
  long i = (long)blockIdx.x * 256 + threadIdx.x;
  d[i] = s[i];
}

// LN stats over D=1024: stats[row] = {mean, rsqrt(var+eps)}. fp32 input.
__global__ __launch_bounds__(256) void ln_stats_f32(
    const float* __restrict__ x, float2* __restrict__ stats)
{
  int row = blockIdx.x, t = threadIdx.x;
  const float* xr = x + (long)row * 1024;
  float4 a = *(const float4*)(xr + t * 4);
  float s = a.x + a.y + a.z + a.w;
  float q = a.x * a.x + a.y * a.y + a.z * a.z + a.w * a.w;
  for (int o = 32; o > 0; o >>= 1) { s += __shfl_down(s, o); q += __shfl_down(q, o); }
  __shared__ float sm[8];
  if ((t & 63) == 0) { sm[t >> 6] = s; sm[4 + (t >> 6)] = q; }
  __syncthreads();
  if (t == 0) {
    s = sm[0] + sm[1] + sm[2] + sm[3];
    q = sm[4] + sm[5] + sm[6] + sm[7];
    float mean = s * (1.0f / 1024.0f);
    float var  = q * (1.0f / 1024.0f) - mean * mean;
    stats[row] = make_float2(mean, rsqrtf(var + 1e-5f));
  }
}

// LN stats, bf16 input.
__global__ __launch_bounds__(256) void ln_stats_b16(
    const bf16* __restrict__ x, float2* __restrict__ stats)
{
  int row = blockIdx.x, t = threadIdx.x;
  const bf16* xr = x + (long)row * 1024;
  float v[4];
#pragma unroll
  for (int i = 0; i < 4; i++) v[i] = b2f(xr[t * 4 + i]);
  float s = v[0] + v[1] + v[2] + v[3];
  float q = v[0] * v[0] + v[1] * v[1] + v[2] * v[2] + v[3] * v[3];
  for (int o = 32; o > 0; o >>= 1) { s += __shfl_down(s, o); q += __shfl_down(q, o); }
  __shared__ float sm[8];
  if ((t & 63) == 0) { sm[t >> 6] = s; sm[4 + (t >> 6)] = q; }
  __syncthreads();
  if (t == 0) {
    s = sm[0] + sm[1] + sm[2] + sm[3];
    q = sm[4] + sm[5] + sm[6] + sm[7];
    float mean = s * (1.0f / 1024.0f);
    float var  = q * (1.0f / 1024.0f) - mean * mean;
    stats[row] = make_float2(mean, rsqrtf(var + 1e-5f));
  }
}

// softmax over 256 contiguous elems per row (q~, per-head). In place, bf16.
__global__ __launch_bounds__(256) void qsoftmax256(bf16* __restrict__ q)
{
  long idx = (long)blockIdx.x * 256 + threadIdx.x;
  int t = threadIdx.x;
  float v = expf(0.25f * b2f(q[idx]));
  float s = v;
  for (int o = 32; o > 0; o >>= 1) s += __shfl_down(s, o);
  __shared__ float sm[4];
  if ((t & 63) == 0) sm[t >> 6] = s;
  __syncthreads();
  float tot = sm[0] + sm[1] + sm[2] + sm[3];
  q[idx] = f2b(v / tot);
}

// k softmax on kT [rows][4096]: row-softmax exp(0.25x)/rowsum, in place.
__global__ __launch_bounds__(256) void ksoftmaxT(bf16* __restrict__ kT)
{
  long base = (long)blockIdx.x * 4096;
  int t = threadIdx.x;
  float loc[16];
  float s = 0.0f;
#pragma unroll
  for (int i = 0; i < 16; i++) {
    loc[i] = expf(0.25f * b2f(kT[base + t + i * 256]));
    s += loc[i];
  }
  for (int o = 32; o > 0; o >>= 1) s += __shfl_down(s, o);
  __shared__ float sm[4];
  if ((t & 63) == 0) sm[t >> 6] = s;
  __syncthreads();
  float inv = 1.0f / (sm[0] + sm[1] + sm[2] + sm[3]);
#pragma unroll
  for (int i = 0; i < 16; i++)
    kT[base + t + i * 256] = f2b(loc[i] * inv);
}

// ctx reduce: CTX[i] = sum_kc G[kc*262144 + i], i in [0, 262144).
__global__ __launch_bounds__(256) void reduce_ctx(
    const bf16* __restrict__ G, bf16* __restrict__ CTX)
{
  long i = (long)blockIdx.x * 256 + threadIdx.x;
  float s = 0.0f;
#pragma unroll
  for (int kc = 0; kc < 8; kc++) s += b2f(G[kc * 262144 + i]);
  CTX[i] = f2b(s);
}

// OB[n] = sum_k b2[k] * WDT[n][k] + bd[n]   (n = blockIdx.x, 1024 blocks)
__global__ __launch_bounds__(256) void out_bias(
    const float* __restrict__ b2, const bf16* __restrict__ WDT,
    const float* __restrict__ bd, float* __restrict__ OB)
{
  int n = blockIdx.x, t = threadIdx.x;
  const bf16* wr = WDT + (long)n * 1024;
  float s = 0.0f;
#pragma unroll
  for (int i = 0; i < 4; i++) {
    int k = t * 4 + i;
    s += b2[k] * b2f(wr[k]);
  }
  for (int o = 32; o > 0; o >>= 1) s += __shfl_down(s, o);
  __shared__ float sm[4];
  if ((t & 63) == 0) sm[t >> 6] = s;
  __syncthreads();
  if (t == 0) OB[n] = sm[0] + sm[1] + sm[2] + sm[3] + bd[n];
}

// out[r][c] = b[c] over 1024x1024 fp32 (seed for atomic split-K GEMMs)
__global__ __launch_bounds__(256) void bias_bcast(
    const float* __restrict__ b, float* __restrict__ out)
{
  long i = ((long)blockIdx.x * 256 + threadIdx.x) * 4;
  *(float4*)(out + i) = *(const float4*)(b + (int)(i & 1023));
}

extern "C" void kernel_launch(void* const* d_in, const int* in_sizes, int n_in,
                              void* d_out, int out_size, void* d_ws, size_t ws_size,
                              hipStream_t stream) {
  const float* x    = (const float*)d_in[0];
  const float* ln1g = (const float*)d_in[1];
  const float* ln1b = (const float*)d_in[2];
  const float* wq   = (const float*)d_in[3];
  const float* wk   = (const float*)d_in[4];
  const float* wv   = (const float*)d_in[5];
  const float* wo   = (const float*)d_in[6];
  const float* bo   = (const float*)d_in[7];
  const float* ln2g = (const float*)d_in[8];
  const float* ln2b = (const float*)d_in[9];
  const float* wff1 = (const float*)d_in[10];
  const float* bff1 = (const float*)d_in[11];
  const float* wff2 = (const float*)d_in[12];
  const float* bff2 = (const float*)d_in[13];
  const float* wd   = (const float*)d_in[14];
  const float* bd   = (const float*)d_in[15];

  // d_out (64MB fp32) as scratch: first half xb (bf16 x), second half x2 (bf16).
  bf16* xb = (bf16*)d_out;                            // 16384x1024 bf16
  bf16* x2 = (bf16*)d_out + (size_t)16384 * 1024;     // 16384x1024 bf16
  float* outf = (float*)d_out;

  char* wsp = (char*)d_ws;
  size_t off = 0;
  auto alloc = [&](size_t bytes) -> void* {
    void* p = wsp + off; off += (bytes + 255) & ~(size_t)255; return p;
  };
  bf16*   S1  = (bf16*)alloc((size_t)8 * 1024 * 1024);   // kT_h -> q_h | wff1T
  bf16*   S2  = (bf16*)alloc((size_t)8 * 1024 * 1024);   // vT_h -> attn_h | WCDT
  bf16*   G   = (bf16*)alloc((size_t)8 * 1024 * 1024);   // ctx partials | g chunk
  bf16*   CTX = (bf16*)alloc((size_t)4 * 256 * 256 * 2); // ctx_h | OB overlay (FFN)
  bf16*   W1  = (bf16*)alloc((size_t)1024 * 256 * 2);    // weight slice (BT form)
  bf16*   WDT = (bf16*)alloc((size_t)1024 * 1024 * 2);   // wd^T
  bf16*   XS  = (bf16*)alloc((size_t)1024 * 1024 * 2);   // x2 tail rescue (chunk 15)
  float2* st1 = (float2*)alloc((size_t)16384 * 8);
  float2* st2 = (float2*)alloc((size_t)16384 * 8);
  float*  OB  = (float*)CTX;  // 4KB, CTX dead during FFN
  // total ws = 30,670,848 B — identical to the proven baseline footprint.

  const long SA = (long)4096 * 1024;  // x batch stride (elements)
  const long PH = (long)256 * 4096;   // per-batch [e][n] stride
  dim3 tb(32, 8);
  const bf16* nb = nullptr;

  // ---- xb = bf16(x); LN1 stats (fp32 x) ----
  cvt_f2b<<<8192, 256, 0, stream>>>(x, xb);
  ln_stats_f32<<<16384, 256, 0, stream>>>(x, st1);

  // ---- attention, per head; x2 accumulates into second half of d_out ----
  for (int h = 0; h < 4; h++) {
    // kT_h = (LN1(x) @ wk[:,h])^T -> S1 [4b][256e][4096n]; row softmax
    transpose_f2b<<<dim3(8, 32), tb, 0, stream>>>(wk + h * 256, W1, 1024, 1024);
    gemm_bt<1, 1, 0, 0><<<dim3(2, 32, 4), 256, 0, stream>>>(x, W1, S1,
        1024, 1024, 1024, 4096, 2, 0, SA, 0, 0, 0, PH,
        nullptr, nb, 0, st1, ln1g, ln1b);
    ksoftmaxT<<<1024, 256, 0, stream>>>(S1);

    // vT_h -> S2
    transpose_f2b<<<dim3(8, 32), tb, 0, stream>>>(wv + h * 256, W1, 1024, 1024);
    gemm_bt<1, 1, 0, 0><<<dim3(2, 32, 4), 256, 0, stream>>>(x, W1, S2,
        1024, 1024, 1024, 4096, 2, 0, SA, 0, 0, 0, PH,
        nullptr, nb, 0, st1, ln1g, ln1b);

    // ctx partials: G[kc][b][e][d] = sum_{n in kc} vT[e][n] * k~T[d][n]
    gemm_bt<0, 0, 0, 0><<<dim3(2, 2, 32), 256, 0, stream>>>(S2, S1, G,
        512, 4096, 4096, 256, 3, PH, 512, PH, 512, 65536, 262144,
        nullptr, nb, 0, nullptr, nullptr, nullptr);
    reduce_ctx<<<1024, 256, 0, stream>>>(G, CTX);

    // q_h = LN1(x)@wq[:,h] -> S1 [4b][4096][256]; softmax over dh
    transpose_f2b<<<dim3(8, 32), tb, 0, stream>>>(wq + h * 256, W1, 1024, 1024);
    gemm_bt<0, 1, 0, 0><<<dim3(2, 32, 4), 256, 0, stream>>>(x, W1, S1,
        1024, 1024, 1024, 256, 2, 0, SA, 0, 0, 0, (long)4096 * 256,
        nullptr, nb, 0, st1, ln1g, ln1b);
    qsoftmax256<<<16384, 256, 0, stream>>>(S1);

    // attn_h[n][e] = sum_d q~[n][d] * ctx[e][d] -> S2 [4b][4096][256]
    gemm_bt<0, 0, 0, 0><<<dim3(2, 32, 4), 256, 0, stream>>>(S1, CTX, S2,
        256, 256, 256, 256, 2, 0, (long)4096 * 256, 0, 65536, 0, (long)4096 * 256,
        nullptr, nb, 0, nullptr, nullptr, nullptr);

    // x2 += attn_h @ wo[h rows]  (h==0 seeds xb + bo)
    transpose_f2b<<<dim3(32, 8), tb, 0, stream>>>(wo + (size_t)h * 256 * 1024, W1, 1024, 256);
    gemm_bt<0, 0, 0, 0><<<dim3(8, 128, 1), 256, 0, stream>>>(S2, W1, x2,
        256, 256, 256, 1024, 2, 0, 0, 0, 0, 0, 0,
        (h == 0) ? bo : nullptr, (h == 0) ? xb : x2, 0, nullptr, nullptr, nullptr);
  }

  // ---- FFN + trailing dense, fused via out = x2@wd + g@(wff2@wd) + OB ----
  ln_stats_b16<<<16384, 256, 0, stream>>>(x2, st2);
  transpose_f2b<<<dim3(128, 32), tb, 0, stream>>>(wff1, S1, 4096, 1024);  // S1 = wff1T
  transpose_f2b<<<dim3(32, 32), tb, 0, stream>>>(wd, WDT, 1024, 1024);    // WDT = wd^T
  // S2 = WCDT: WCD[k][n] = sum_j wff2[k][j] * wd[j][n]; TRANSC stores [n][k]
  // (BT form, ldc = 4096). A = wff2 fp32 [4096][1024], B = WDT.
  gemm_bt<1, 1, 0, 0><<<dim3(8, 32, 1), 256, 0, stream>>>(wff2, WDT, S2,
      1024, 1024, 1024, 4096, 0, 0, 0, 0, 0, 0, 0,
      nullptr, nb, 0, nullptr, nullptr, nullptr);
  // OB[n] = b_ff2 @ wd + b_d
  out_bias<<<1024, 256, 0, stream>>>(bff2, WDT, bd, OB);

  for (int R = 0; R < 16; R++) {
    const bf16* xr = x2 + (size_t)R * 1024 * 1024;  // x2 rows (bf16)
    if (R == 15)  // rescue x2 rows [15360,16384) before out_R overwrites them
      copy16<<<512, 256, 0, stream>>>((const float4*)xr, (float4*)XS);
    // g = gelu(LN2(x2_R) @ wff1T + b1) -> G [1024][4096]
    gemm_bt<0, 0, 0, 0><<<dim3(32, 8, 1), 256, 0, stream>>>(xr, S1, G,
        1024, 1024, 1024, 4096, 2, 0, 0, 0, 0, 0, 0,
        bff1, nb, 1, st2 + R * 1024, ln2g, ln2b);
    // out_R = OB (seed); placed after gemm1(R) — chunk 15's out-write covers
    // x2 rows gemm1(15) reads.
    bias_bcast<<<1024, 256, 0, stream>>>(OB, outf + (size_t)R * 1024 * 1024);
    // out_R += g @ WCDT   (split-K: z=8 slices of K=512 -> 512 blocks, atomics)
    gemm_bt<0, 0, 1, 1><<<dim3(8, 8, 8), 256, 0, stream>>>(G, S2,
        outf + (size_t)R * 1024 * 1024,
        512, 4096, 4096, 1024, 3, 0, 512, 0, 512, 0, 0,
        nullptr, nb, 0, nullptr, nullptr, nullptr);
    // out_R += x2_R @ wd  (split-K: z=4 slices of K=256 -> 256 blocks, atomics)
    gemm_bt<0, 0, 1, 1><<<dim3(8, 8, 4), 256, 0, stream>>>(
        (R == 15) ? XS : xr, WDT,
        outf + (size_t)R * 1024 * 1024,
        256, 1024, 1024, 1024, 2, 0, 256, 0, 256, 0, 0,
        nullptr, nb, 0, nullptr, nullptr, nullptr);
  }
}

// Round 3
// 2467.846 us; speedup vs baseline: 1.4920x; 1.1767x over previous
//
#include <hip/hip_runtime.h>
#include <hip/hip_bf16.h>

// LinearformerBlock on MI355X (gfx950). I/O is FP32 (per reference dtypes);
// internals bf16 MFMA with fp32 accumulation. B=4,N=4096,D=1024,H=4,DH=256,FF=4096.
//
// ws = 30,670,848 B — EXACTLY the proven baseline footprint.
//
// d_out (64MB fp32) doubles as scratch: first half = xln (bf16 LN1(x)),
// second half = x2 (bf16). Final dense writes fp32 rows forward-order.
// Clobber analysis: out chunk R writes rows [1024R,1024R+1024), clobbering
// x2 rows [2048R-16384, 2048R-14336) — always below later chunks' first
// needed row 1024(R+1). Chunk R's own x2 data is rescued by copy_cols into
// G cols [4096:5120) BEFORE any out-write of chunk R. xln dead in FFN.
//
// r6: FFN algebra out = x2@wd + g@(wff2@wd) + (b2@wd+bd); split-K atomics.
//     3682 -> 2904 us.
// r7 (this round):
//  (a) K-concat: G = [1024][5120] = [g | x2_R]; WB = [WCD^T | wd^T]
//      [1024][5120]. ONE split-K GEMM (z=8, slice 640) replaces gDelta(z8)
//      + x2@wd(z4): deletes 32 MB/chunk of atomic RMW traffic + a launch.
//  (b) LN1 hoisted: xln = bf16(LN1(x)) computed once; the 12 q/k/v GEMMs
//      read bf16 A (32 MB vs 64 MB fp32) with no per-k-step LN VALU.
//      h==0 wo-GEMM residual reads fp32 x directly via RESF32 flag.

typedef __hip_bfloat16 bf16;
typedef __attribute__((ext_vector_type(8))) short short8;
typedef __attribute__((ext_vector_type(4))) float floatx4;

__device__ __forceinline__ float b2f(bf16 x) { return __bfloat162float(x); }
__device__ __forceinline__ bf16 f2b(float x) { return __float2bfloat16(x); }
__device__ __forceinline__ float s2f(short s) {
  unsigned int u = ((unsigned int)(unsigned short)s) << 16;
  return __uint_as_float(u);
}
__device__ __forceinline__ short f2s(float f) {
  bf16 h = __float2bfloat16(f);
  return *reinterpret_cast<short*>(&h);
}
__device__ __forceinline__ float gelu_f(float x) {
  float u = 0.7978845608028654f * (x + 0.044715f * x * x * x);
  return 0.5f * x * (1.0f + tanhf(u));
}

// ---------------------------------------------------------------------------
// GEMM: C[m][n] = sum_k A'[m][k] * BT[n][k]   (A' = LN(A) if stats!=null)
// 128x128 tile, BK=32, 4 waves x (4x4) 16x16x32 bf16 MFMA.
// AFP32: A operand is fp32. CFP32: store C fp32. TRANSC: write C transposed.
// ATOM: epilogue atomicAdds into fp32 C (split-K; bias/res/act null/0).
// RESF32: res pointer is fp32 (residual read from original x).
// ---------------------------------------------------------------------------
template <int TRANSC, int AFP32, int CFP32, int ATOM, int RESF32 = 0>
__global__ __launch_bounds__(256) void gemm_bt(
    const void* __restrict__ Aop, const bf16* __restrict__ BT, void* Cv,
    int K, int lda, int ldb, int ldc, int zshift,
    long saA, long shA, long saB, long shB, long saC, long shC,
    const float* __restrict__ bias, const bf16* res, int act,
    const float2* stats, const float* __restrict__ gamma,
    const float* __restrict__ beta)
{
  int z = blockIdx.z;
  int zb = z >> zshift, zh = z & ((1 << zshift) - 1);
  long offA = (long)zb * saA + (long)zh * shA;
  long offC = (long)zb * saC + (long)zh * shC;
  const float* Af = (const float*)Aop + offA;
  const bf16*  Ab = (const bf16*)Aop + offA;
  BT += (long)zb * saB + (long)zh * shB;
  bf16*  C  = (bf16*)Cv + offC;
  float* Cf = (float*)Cv + offC;
  const bf16*  resb = res ? res + offC : nullptr;
  const float* resf = res ? (const float*)res + offC : nullptr;
  if (stats) stats += offA / lda;

  __shared__ bf16 As[128 * 32];
  __shared__ bf16 Bs[128 * 32];
  __shared__ bf16 TC[TRANSC ? 128 * 136 : 2];

  const int t = threadIdx.x;
  const int w = t >> 6, l = t & 63;
  const int m0 = blockIdx.y * 128, n0 = blockIdx.x * 128;
  const int wm = (w >> 1) * 64, wn = (w & 1) * 64;
  const int lr = l & 15, lq = l >> 4;

  floatx4 acc[4][4] = {};

  const int sr = t >> 2;        // staging row within half-tile (0..63)
  const int sc = (t & 3) * 8;   // staging col (0,8,16,24)
  const int rowA0 = m0 + sr, rowA1 = m0 + 64 + sr;
  const long o0 = (long)rowA0 * lda + sc;
  const long o1 = (long)rowA1 * lda + sc;

  const bf16* Bp0 = BT + (long)(n0 + sr) * ldb + sc;
  const bf16* Bp1 = BT + (long)(n0 + 64 + sr) * ldb + sc;

  float2 st0, st1;
  if (stats) { st0 = stats[rowA0]; st1 = stats[rowA1]; }

  for (int k0 = 0; k0 < K; k0 += 32) {
    short8 ra0, ra1;
    if constexpr (AFP32) {
      float4 a00 = *(const float4*)(Af + o0 + k0);
      float4 a01 = *(const float4*)(Af + o0 + k0 + 4);
      float4 a10 = *(const float4*)(Af + o1 + k0);
      float4 a11 = *(const float4*)(Af + o1 + k0 + 4);
      float v0[8] = {a00.x, a00.y, a00.z, a00.w, a01.x, a01.y, a01.z, a01.w};
      float v1[8] = {a10.x, a10.y, a10.z, a10.w, a11.x, a11.y, a11.z, a11.w};
      if (stats) {
        float4 g0 = *(const float4*)(gamma + k0 + sc);
        float4 g1 = *(const float4*)(gamma + k0 + sc + 4);
        float4 e0 = *(const float4*)(beta + k0 + sc);
        float4 e1 = *(const float4*)(beta + k0 + sc + 4);
        float gv[8] = {g0.x, g0.y, g0.z, g0.w, g1.x, g1.y, g1.z, g1.w};
        float ev[8] = {e0.x, e0.y, e0.z, e0.w, e1.x, e1.y, e1.z, e1.w};
#pragma unroll
        for (int i = 0; i < 8; i++) {
          v0[i] = (v0[i] - st0.x) * st0.y * gv[i] + ev[i];
          v1[i] = (v1[i] - st1.x) * st1.y * gv[i] + ev[i];
        }
      }
#pragma unroll
      for (int i = 0; i < 8; i++) { ra0[i] = f2s(v0[i]); ra1[i] = f2s(v1[i]); }
    } else {
      ra0 = *(const short8*)(Ab + o0 + k0);
      ra1 = *(const short8*)(Ab + o1 + k0);
      if (stats) {
        float4 g0 = *(const float4*)(gamma + k0 + sc);
        float4 g1 = *(const float4*)(gamma + k0 + sc + 4);
        float4 e0 = *(const float4*)(beta + k0 + sc);
        float4 e1 = *(const float4*)(beta + k0 + sc + 4);
        float gv[8] = {g0.x, g0.y, g0.z, g0.w, g1.x, g1.y, g1.z, g1.w};
        float ev[8] = {e0.x, e0.y, e0.z, e0.w, e1.x, e1.y, e1.z, e1.w};
#pragma unroll
        for (int i = 0; i < 8; i++) {
          ra0[i] = f2s((s2f(ra0[i]) - st0.x) * st0.y * gv[i] + ev[i]);
          ra1[i] = f2s((s2f(ra1[i]) - st1.x) * st1.y * gv[i] + ev[i]);
        }
      }
    }
    short8 rb0 = *(const short8*)(Bp0 + k0);
    short8 rb1 = *(const short8*)(Bp1 + k0);
    __syncthreads();  // prev iter's LDS reads done
    *(short8*)&As[t * 8]        = ra0;
    *(short8*)&As[2048 + t * 8] = ra1;
    *(short8*)&Bs[t * 8]        = rb0;
    *(short8*)&Bs[2048 + t * 8] = rb1;
    __syncthreads();
    short8 af[4], bfr[4];
#pragma unroll
    for (int i = 0; i < 4; i++) {
      af[i]  = *(const short8*)&As[(wm + i * 16 + lr) * 32 + lq * 8];
      bfr[i] = *(const short8*)&Bs[(wn + i * 16 + lr) * 32 + lq * 8];
    }
#pragma unroll
    for (int i = 0; i < 4; i++)
#pragma unroll
      for (int j = 0; j < 4; j++)
        acc[i][j] = __builtin_amdgcn_mfma_f32_16x16x32_bf16(af[i], bfr[j], acc[i][j], 0, 0, 0);
  }

  if constexpr (TRANSC) {
    // C/D layout: col(n) = lane&15, row(m) = (lane>>4)*4 + reg.
#pragma unroll
    for (int i = 0; i < 4; i++) {
      int rloc = wm + i * 16 + lq * 4;
#pragma unroll
      for (int j = 0; j < 4; j++) {
        int cloc = wn + j * 16 + lr;
#pragma unroll
        for (int r = 0; r < 4; r++)
          TC[cloc * 136 + rloc + r] = f2b(acc[i][j][r]);
      }
    }
    __syncthreads();
    long base = (long)n0 * ldc + m0;
#pragma unroll
    for (int p = 0; p < 8; p++) {
      int er = (t >> 4) + p * 16;   // local e row (0..127)
      int mc = (t & 15) * 8;        // local m col
      *(short8*)(C + base + (long)er * ldc + mc) = *(const short8*)&TC[er * 136 + mc];
    }
    return;
  }

#pragma unroll
  for (int i = 0; i < 4; i++) {
    int row0 = m0 + wm + i * 16 + lq * 4;
#pragma unroll
    for (int j = 0; j < 4; j++) {
      int col = n0 + wn + j * 16 + lr;
      if constexpr (ATOM) {
#pragma unroll
        for (int r = 0; r < 4; r++) {
          long idx = (long)(row0 + r) * ldc + col;
          atomicAdd(&Cf[idx], acc[i][j][r]);
        }
      } else {
        float bv = bias ? bias[col] : 0.0f;
#pragma unroll
        for (int r = 0; r < 4; r++) {
          float v = acc[i][j][r] + bv;
          long idx = (long)(row0 + r) * ldc + col;
          if (res) {
            if constexpr (RESF32) v += resf[idx]; else v += b2f(resb[idx]);
          }
          if (act) v = gelu_f(v);
          if constexpr (CFP32) Cf[idx] = v; else C[idx] = f2b(v);
        }
      }
    }
  }
}

// ---------------------------------------------------------------------------
// Tiled transpose fp32 -> bf16: dst[c][r] = (bf16)src[r][c].
// Grid: (Csrc/32, Rsrc/32). Block (32,8).
// ---------------------------------------------------------------------------
__global__ void transpose_f2b(const float* __restrict__ src, bf16* __restrict__ dst,
                              int lsrc, int ldst)
{
  __shared__ bf16 tile[32][33];
  int tx = threadIdx.x, ty = threadIdx.y;
  int c0 = blockIdx.x * 32, r0 = blockIdx.y * 32;
#pragma unroll
  for (int j = 0; j < 4; j++)
    tile[ty + j * 8][tx] = f2b(src[(long)(r0 + ty + j * 8) * lsrc + c0 + tx]);
  __syncthreads();
#pragma unroll
  for (int j = 0; j < 4; j++)
    dst[(long)(c0 + ty + j * 8) * ldst + r0 + tx] = tile[tx][ty + j * 8];
}

// copy x2 chunk row r cols [0,1024) -> G row r cols [4096,5120).
__global__ __launch_bounds__(128) void copy_cols(const bf16* __restrict__ s,
                                                 bf16* __restrict__ d)
{
  int r = blockIdx.x, c = threadIdx.x * 8;
  *(short8*)(d + (long)r * 5120 + 4096 + c) = *(const short8*)(s + (long)r * 1024 + c);
}

// LN stats over D=1024: stats[row] = {mean, rsqrt(var+eps)}. fp32 input.
__global__ __launch_bounds__(256) void ln_stats_f32(
    const float* __restrict__ x, float2* __restrict__ stats)
{
  int row = blockIdx.x, t = threadIdx.x;
  const float* xr = x + (long)row * 1024;
  float4 a = *(const float4*)(xr + t * 4);
  float s = a.x + a.y + a.z + a.w;
  float q = a.x * a.x + a.y * a.y + a.z * a.z + a.w * a.w;
  for (int o = 32; o > 0; o >>= 1) { s += __shfl_down(s, o); q += __shfl_down(q, o); }
  __shared__ float sm[8];
  if ((t & 63) == 0) { sm[t >> 6] = s; sm[4 + (t >> 6)] = q; }
  __syncthreads();
  if (t == 0) {
    s = sm[0] + sm[1] + sm[2] + sm[3];
    q = sm[4] + sm[5] + sm[6] + sm[7];
    float mean = s * (1.0f / 1024.0f);
    float var  = q * (1.0f / 1024.0f) - mean * mean;
    stats[row] = make_float2(mean, rsqrtf(var + 1e-5f));
  }
}

// xln[i] = bf16((x[i]-mu)*rstd*g+b), 8 elems/thread (all within one row).
__global__ __launch_bounds__(256) void ln_apply(
    const float* __restrict__ x, const float2* __restrict__ stats,
    const float* __restrict__ g, const float* __restrict__ b,
    bf16* __restrict__ out)
{
  long i = ((long)blockIdx.x * 256 + threadIdx.x) * 8;
  int row = (int)(i >> 10), col = (int)(i & 1023);
  float2 st = stats[row];
  float4 a0 = *(const float4*)(x + i);
  float4 a1 = *(const float4*)(x + i + 4);
  float4 g0 = *(const float4*)(g + col);
  float4 g1 = *(const float4*)(g + col + 4);
  float4 b0 = *(const float4*)(b + col);
  float4 b1 = *(const float4*)(b + col + 4);
  float av[8] = {a0.x, a0.y, a0.z, a0.w, a1.x, a1.y, a1.z, a1.w};
  float gv[8] = {g0.x, g0.y, g0.z, g0.w, g1.x, g1.y, g1.z, g1.w};
  float bv[8] = {b0.x, b0.y, b0.z, b0.w, b1.x, b1.y, b1.z, b1.w};
  short8 o;
#pragma unroll
  for (int j = 0; j < 8; j++)
    o[j] = f2s((av[j] - st.x) * st.y * gv[j] + bv[j]);
  *(short8*)(out + i) = o;
}

// LN stats, bf16 input.
__global__ __launch_bounds__(256) void ln_stats_b16(
    const bf16* __restrict__ x, float2* __restrict__ stats)
{
  int row = blockIdx.x, t = threadIdx.x;
  const bf16* xr = x + (long)row * 1024;
  float v[4];
#pragma unroll
  for (int i = 0; i < 4; i++) v[i] = b2f(xr[t * 4 + i]);
  float s = v[0] + v[1] + v[2] + v[3];
  float q = v[0] * v[0] + v[1] * v[1] + v[2] * v[2] + v[3] * v[3];
  for (int o = 32; o > 0; o >>= 1) { s += __shfl_down(s, o); q += __shfl_down(q, o); }
  __shared__ float sm[8];
  if ((t & 63) == 0) { sm[t >> 6] = s; sm[4 + (t >> 6)] = q; }
  __syncthreads();
  if (t == 0) {
    s = sm[0] + sm[1] + sm[2] + sm[3];
    q = sm[4] + sm[5] + sm[6] + sm[7];
    float mean = s * (1.0f / 1024.0f);
    float var  = q * (1.0f / 1024.0f) - mean * mean;
    stats[row] = make_float2(mean, rsqrtf(var + 1e-5f));
  }
}

// softmax over 256 contiguous elems per row (q~, per-head). In place, bf16.
__global__ __launch_bounds__(256) void qsoftmax256(bf16* __restrict__ q)
{
  long idx = (long)blockIdx.x * 256 + threadIdx.x;
  int t = threadIdx.x;
  float v = expf(0.25f * b2f(q[idx]));
  float s = v;
  for (int o = 32; o > 0; o >>= 1) s += __shfl_down(s, o);
  __shared__ float sm[4];
  if ((t & 63) == 0) sm[t >> 6] = s;
  __syncthreads();
  float tot = sm[0] + sm[1] + sm[2] + sm[3];
  q[idx] = f2b(v / tot);
}

// k softmax on kT [rows][4096]: row-softmax exp(0.25x)/rowsum, in place.
__global__ __launch_bounds__(256) void ksoftmaxT(bf16* __restrict__ kT)
{
  long base = (long)blockIdx.x * 4096;
  int t = threadIdx.x;
  float loc[16];
  float s = 0.0f;
#pragma unroll
  for (int i = 0; i < 16; i++) {
    loc[i] = expf(0.25f * b2f(kT[base + t + i * 256]));
    s += loc[i];
  }
  for (int o = 32; o > 0; o >>= 1) s += __shfl_down(s, o);
  __shared__ float sm[4];
  if ((t & 63) == 0) sm[t >> 6] = s;
  __syncthreads();
  float inv = 1.0f / (sm[0] + sm[1] + sm[2] + sm[3]);
#pragma unroll
  for (int i = 0; i < 16; i++)
    kT[base + t + i * 256] = f2b(loc[i] * inv);
}

// ctx reduce: CTX[i] = sum_kc G[kc*262144 + i], i in [0, 262144).
__global__ __launch_bounds__(256) void reduce_ctx(
    const bf16* __restrict__ G, bf16* __restrict__ CTX)
{
  long i = (long)blockIdx.x * 256 + threadIdx.x;
  float s = 0.0f;
#pragma unroll
  for (int kc = 0; kc < 8; kc++) s += b2f(G[kc * 262144 + i]);
  CTX[i] = f2b(s);
}

// OB[n] = sum_k b2[k] * wdt[n][k] + bd[n]   (n = blockIdx.x; wdt row stride ld)
__global__ __launch_bounds__(256) void out_bias(
    const float* __restrict__ b2, const bf16* __restrict__ wdt, int ld,
    const float* __restrict__ bd, float* __restrict__ OB)
{
  int n = blockIdx.x, t = threadIdx.x;
  const bf16* wr = wdt + (long)n * ld;
  float s = 0.0f;
#pragma unroll
  for (int i = 0; i < 4; i++) {
    int k = t * 4 + i;
    s += b2[k] * b2f(wr[k]);
  }
  for (int o = 32; o > 0; o >>= 1) s += __shfl_down(s, o);
  __shared__ float sm[4];
  if ((t & 63) == 0) sm[t >> 6] = s;
  __syncthreads();
  if (t == 0) OB[n] = sm[0] + sm[1] + sm[2] + sm[3] + bd[n];
}

// out[r][c] = b[c] over 1024x1024 fp32 (seed for atomic split-K GEMMs)
__global__ __launch_bounds__(256) void bias_bcast(
    const float* __restrict__ b, float* __restrict__ out)
{
  long i = ((long)blockIdx.x * 256 + threadIdx.x) * 4;
  *(float4*)(out + i) = *(const float4*)(b + (int)(i & 1023));
}

extern "C" void kernel_launch(void* const* d_in, const int* in_sizes, int n_in,
                              void* d_out, int out_size, void* d_ws, size_t ws_size,
                              hipStream_t stream) {
  const float* x    = (const float*)d_in[0];
  const float* ln1g = (const float*)d_in[1];
  const float* ln1b = (const float*)d_in[2];
  const float* wq   = (const float*)d_in[3];
  const float* wk   = (const float*)d_in[4];
  const float* wv   = (const float*)d_in[5];
  const float* wo   = (const float*)d_in[6];
  const float* bo   = (const float*)d_in[7];
  const float* ln2g = (const float*)d_in[8];
  const float* ln2b = (const float*)d_in[9];
  const float* wff1 = (const float*)d_in[10];
  const float* bff1 = (const float*)d_in[11];
  const float* wff2 = (const float*)d_in[12];
  const float* bff2 = (const float*)d_in[13];
  const float* wd   = (const float*)d_in[14];
  const float* bd   = (const float*)d_in[15];

  // d_out (64MB fp32) as scratch: first half xln (bf16 LN1(x)), second x2.
  bf16* xln = (bf16*)d_out;                           // 16384x1024 bf16
  bf16* x2  = (bf16*)d_out + (size_t)16384 * 1024;    // 16384x1024 bf16
  float* outf = (float*)d_out;

  char* wsp = (char*)d_ws;
  size_t off = 0;
  auto alloc = [&](size_t bytes) -> void* {
    void* p = wsp + off; off += (bytes + 255) & ~(size_t)255; return p;
  };
  bf16*   S1  = (bf16*)alloc((size_t)8 * 1024 * 1024);    // kT_h -> q_h | wff1T
  bf16*   S2  = (bf16*)alloc((size_t)10 * 1024 * 1024);   // vT_h -> attn_h | WB
  bf16*   G   = (bf16*)alloc((size_t)10 * 1024 * 1024);   // ctx partials | [g|x2_R]
  bf16*   CTX = (bf16*)alloc((size_t)4 * 256 * 256 * 2);  // ctx_h | OB overlay
  bf16*   W1  = (bf16*)alloc((size_t)1024 * 256 * 2);     // weight slice (BT form)
  float2* st1 = (float2*)alloc((size_t)16384 * 8);
  float2* st2 = (float2*)alloc((size_t)16384 * 8);
  bf16*   WB  = S2;           // FFN: [1024][5120] = [WCD^T | wd^T]
  float*  OB  = (float*)CTX;  // 4KB, CTX dead during FFN
  // total ws = 30,670,848 B — identical to the proven baseline footprint.

  const long SA = (long)4096 * 1024;  // per-batch row-block stride (elements)
  const long PH = (long)256 * 4096;   // per-batch [e][n] stride
  dim3 tb(32, 8);
  const bf16* nb = nullptr;

  // ---- LN1 stats + xln = bf16(LN1(x)) ----
  ln_stats_f32<<<16384, 256, 0, stream>>>(x, st1);
  ln_apply<<<8192, 256, 0, stream>>>(x, st1, ln1g, ln1b, xln);

  // ---- attention, per head; x2 accumulates into second half of d_out ----
  for (int h = 0; h < 4; h++) {
    // kT_h = (xln @ wk[:,h])^T -> S1 [4b][256e][4096n]; row softmax
    transpose_f2b<<<dim3(8, 32), tb, 0, stream>>>(wk + h * 256, W1, 1024, 1024);
    gemm_bt<1, 0, 0, 0><<<dim3(2, 32, 4), 256, 0, stream>>>(xln, W1, S1,
        1024, 1024, 1024, 4096, 2, 0, SA, 0, 0, 0, PH,
        nullptr, nb, 0, nullptr, nullptr, nullptr);
    ksoftmaxT<<<1024, 256, 0, stream>>>(S1);

    // vT_h -> S2
    transpose_f2b<<<dim3(8, 32), tb, 0, stream>>>(wv + h * 256, W1, 1024, 1024);
    gemm_bt<1, 0, 0, 0><<<dim3(2, 32, 4), 256, 0, stream>>>(xln, W1, S2,
        1024, 1024, 1024, 4096, 2, 0, SA, 0, 0, 0, PH,
        nullptr, nb, 0, nullptr, nullptr, nullptr);

    // ctx partials: G[kc][b][e][d] = sum_{n in kc} vT[e][n] * k~T[d][n]
    gemm_bt<0, 0, 0, 0><<<dim3(2, 2, 32), 256, 0, stream>>>(S2, S1, G,
        512, 4096, 4096, 256, 3, PH, 512, PH, 512, 65536, 262144,
        nullptr, nb, 0, nullptr, nullptr, nullptr);
    reduce_ctx<<<1024, 256, 0, stream>>>(G, CTX);

    // q_h = xln@wq[:,h] -> S1 [4b][4096][256]; softmax over dh
    transpose_f2b<<<dim3(8, 32), tb, 0, stream>>>(wq + h * 256, W1, 1024, 1024);
    gemm_bt<0, 0, 0, 0><<<dim3(2, 32, 4), 256, 0, stream>>>(xln, W1, S1,
        1024, 1024, 1024, 256, 2, 0, SA, 0, 0, 0, (long)4096 * 256,
        nullptr, nb, 0, nullptr, nullptr, nullptr);
    qsoftmax256<<<16384, 256, 0, stream>>>(S1);

    // attn_h[n][e] = sum_d q~[n][d] * ctx[e][d] -> S2 [4b][4096][256]
    gemm_bt<0, 0, 0, 0><<<dim3(2, 32, 4), 256, 0, stream>>>(S1, CTX, S2,
        256, 256, 256, 256, 2, 0, (long)4096 * 256, 0, 65536, 0, (long)4096 * 256,
        nullptr, nb, 0, nullptr, nullptr, nullptr);

    // x2 += attn_h @ wo[h rows]  (h==0 seeds x + bo, x read as fp32)
    transpose_f2b<<<dim3(32, 8), tb, 0, stream>>>(wo + (size_t)h * 256 * 1024, W1, 1024, 256);
    if (h == 0)
      gemm_bt<0, 0, 0, 0, 1><<<dim3(8, 128, 1), 256, 0, stream>>>(S2, W1, x2,
          256, 256, 256, 1024, 2, 0, 0, 0, 0, 0, 0,
          bo, (const bf16*)x, 0, nullptr, nullptr, nullptr);
    else
      gemm_bt<0, 0, 0, 0, 0><<<dim3(8, 128, 1), 256, 0, stream>>>(S2, W1, x2,
          256, 256, 256, 1024, 2, 0, 0, 0, 0, 0, 0,
          nullptr, x2, 0, nullptr, nullptr, nullptr);
  }

  // ---- FFN + trailing dense: out = [g|x2_R] @ [WCD^T|wd^T]^T + OB ----
  ln_stats_b16<<<16384, 256, 0, stream>>>(x2, st2);
  transpose_f2b<<<dim3(128, 32), tb, 0, stream>>>(wff1, S1, 4096, 1024);  // S1 = wff1T
  // WB cols [4096:5120) = wd^T  (row stride 5120)
  transpose_f2b<<<dim3(32, 32), tb, 0, stream>>>(wd, WB + 4096, 1024, 5120);
  // WB cols [0:4096) = WCD^T = (wff2@wd)^T; B operand = wd^T slice of WB.
  gemm_bt<1, 1, 0, 0><<<dim3(8, 32, 1), 256, 0, stream>>>(wff2, WB + 4096, WB,
      1024, 1024, 5120, 5120, 0, 0, 0, 0, 0, 0, 0,
      nullptr, nb, 0, nullptr, nullptr, nullptr);
  // OB[n] = b_ff2 @ wd + b_d
  out_bias<<<1024, 256, 0, stream>>>(bff2, WB + 4096, 5120, bd, OB);

  for (int R = 0; R < 16; R++) {
    const bf16* xr = x2 + (size_t)R * 1024 * 1024;  // x2 rows (bf16)
    // G cols [4096:5120) = x2_R  (also rescues chunk 15 from its own out-write)
    copy_cols<<<1024, 128, 0, stream>>>(xr, G);
    // G cols [0:4096) = gelu(LN2(x2_R) @ wff1T + b1)
    gemm_bt<0, 0, 0, 0><<<dim3(32, 8, 1), 256, 0, stream>>>(xr, S1, G,
        1024, 1024, 1024, 5120, 2, 0, 0, 0, 0, 0, 0,
        bff1, nb, 1, st2 + R * 1024, ln2g, ln2b);
    // out_R = OB (seed); after gemm1(R) — chunk 15's out-write covers x2 rows
    // gemm1(15) reads.
    bias_bcast<<<1024, 256, 0, stream>>>(OB, outf + (size_t)R * 1024 * 1024);
    // out_R += [g|x2_R] @ WB^T  (split-K: z=8 slices of K=640 -> 512 blocks)
    gemm_bt<0, 0, 1, 1><<<dim3(8, 8, 8), 256, 0, stream>>>(G, WB,
        outf + (size_t)R * 1024 * 1024,
        640, 5120, 5120, 1024, 3, 0, 640, 0, 640, 0, 0,
        nullptr, nb, 0, nullptr, nullptr, nullptr);
  }
}

// Round 4
// 2252.528 us; speedup vs baseline: 1.6346x; 1.0956x over previous
//
#include <hip/hip_runtime.h>
#include <hip/hip_bf16.h>

// LinearformerBlock on MI355X (gfx950). I/O is FP32; internals bf16 MFMA with
// fp32 accumulation. B=4,N=4096,D=1024,H=4,DH=256,FF=4096.
//
// ws = 30,670,848 B — EXACTLY the proven baseline footprint.
//
// d_out (64MB fp32) doubles as scratch: first half = xln (bf16 LN1(x)),
// second half = x2 (bf16). Final dense writes fp32 rows forward-order;
// out chunk R clobbers x2 rows [2048R-16384, 2048R-14336) — always below
// later chunks' first needed row. Chunk R's own x2 data is rescued by
// copy_cols into G cols [4096:5120) before any out-write of chunk R.
//
// r6: FFN algebra out = x2@wd + g@(wff2@wd) + (b2@wd+bd). 3682 -> 2904.
// r7: K-concat FFN epilogue + LN1 hoist (xln). 2904 -> 2468.
// r8 (this round) — the 256-block GEMMs are latency-bound (Occ 10.7%, all
// pipes <10%, SQ_LDS_BANK_CONFLICT clipped at 2^20):
//  (a) T2 XOR swizzle of LDS tiles (slot ^= (row>>1)&3): kills the 8-way
//      bank conflict on every ds_read_b128 (16 lanes @ 64B row stride).
//  (b) LDS double-buffer + 2-slice register prefetch, one barrier/slice
//      (loop unrolled x2; ALL K values are multiples of 64: 256/512/640/1024).
//  (c) k/v fused into ONE TRANSC GEMM per head (512 blocks), output
//      [4b][512e][4096n] spanning S1+S2 (contiguous); fused weight slice
//      staged in G's free tail (bytes [9MB,10MB)) — zero ws growth.

typedef __hip_bfloat16 bf16;
typedef __attribute__((ext_vector_type(8))) short short8;
typedef __attribute__((ext_vector_type(4))) float floatx4;

__device__ __forceinline__ float b2f(bf16 x) { return __bfloat162float(x); }
__device__ __forceinline__ bf16 f2b(float x) { return __float2bfloat16(x); }
__device__ __forceinline__ float s2f(short s) {
  unsigned int u = ((unsigned int)(unsigned short)s) << 16;
  return __uint_as_float(u);
}
__device__ __forceinline__ short f2s(float f) {
  bf16 h = __float2bfloat16(f);
  return *reinterpret_cast<short*>(&h);
}
__device__ __forceinline__ float gelu_f(float x) {
  float u = 0.7978845608028654f * (x + 0.044715f * x * x * x);
  return 0.5f * x * (1.0f + tanhf(u));
}

// ---------------------------------------------------------------------------
// GEMM: C[m][n] = sum_k A'[m][k] * BT[n][k]   (A' = LN(A) if stats!=null)
// 128x128 tile, BK=32, 4 waves x (4x4) 16x16x32 bf16 MFMA.
// K must be a multiple of 64 and >= 64.
// LDS: double-buffered As/Bs with XOR-swizzled 16B slots (conflict-free).
// K-loop: 2-slice register prefetch, one barrier per slice.
// AFP32: A operand fp32. CFP32: C fp32. TRANSC: C transposed (bf16, via LDS).
// ATOM: atomicAdd into fp32 C (split-K). RESF32: residual read as fp32.
// ---------------------------------------------------------------------------
template <int TRANSC, int AFP32, int CFP32, int ATOM, int RESF32 = 0>
__global__ __launch_bounds__(256) void gemm_bt(
    const void* __restrict__ Aop, const bf16* __restrict__ BT, void* Cv,
    int K, int lda, int ldb, int ldc, int zshift,
    long saA, long shA, long saB, long shB, long saC, long shC,
    const float* __restrict__ bias, const bf16* res, int act,
    const float2* stats, const float* __restrict__ gamma,
    const float* __restrict__ beta)
{
  int z = blockIdx.z;
  int zb = z >> zshift, zh = z & ((1 << zshift) - 1);
  long offA = (long)zb * saA + (long)zh * shA;
  long offC = (long)zb * saC + (long)zh * shC;
  const float* Af = (const float*)Aop + offA;
  const bf16*  Ab = (const bf16*)Aop + offA;
  BT += (long)zb * saB + (long)zh * shB;
  bf16*  C  = (bf16*)Cv + offC;
  float* Cf = (float*)Cv + offC;
  const bf16*  resb = res ? res + offC : nullptr;
  const float* resf = res ? (const float*)res + offC : nullptr;
  if (stats) stats += offA / lda;

  // smem: As = [2][128*32] at 0, Bs = [2][128*32] at 8192. TRANSC epilogue
  // aliases the whole region as TC[128*136] (safe: used after final barrier).
  __shared__ bf16 smem[TRANSC ? 128 * 136 : 16384];
  bf16* As = smem;
  bf16* Bs = smem + 8192;

  const int t = threadIdx.x;
  const int w = t >> 6, l = t & 63;
  const int m0 = blockIdx.y * 128, n0 = blockIdx.x * 128;
  const int wm = (w >> 1) * 64, wn = (w & 1) * 64;
  const int lr = l & 15, lq = l >> 4;

  floatx4 acc[4][4] = {};

  const int sr = t >> 2;        // staging row within half-tile (0..63)
  const int sc = (t & 3) * 8;   // staging col (0,8,16,24)
  // swizzled 16B-slot store offset: slot s -> s ^ ((row>>1)&3).
  // rows sr and sr+64 share (row>>1)&3 (64/2 % 4 == 0).
  const int stO = sr * 32 + (((t & 3) ^ ((sr >> 1) & 3))) * 8;
  const int rowA0 = m0 + sr, rowA1 = m0 + 64 + sr;
  const long o0 = (long)rowA0 * lda + sc;
  const long o1 = (long)rowA1 * lda + sc;

  const bf16* Bp0 = BT + (long)(n0 + sr) * ldb + sc;
  const bf16* Bp1 = BT + (long)(n0 + 64 + sr) * ldb + sc;

  float2 st0, st1;
  if (stats) { st0 = stats[rowA0]; st1 = stats[rowA1]; }

  auto LOADSET = [&](int k0, short8& ra0, short8& ra1, short8& rb0, short8& rb1) {
    if constexpr (AFP32) {
      float4 a00 = *(const float4*)(Af + o0 + k0);
      float4 a01 = *(const float4*)(Af + o0 + k0 + 4);
      float4 a10 = *(const float4*)(Af + o1 + k0);
      float4 a11 = *(const float4*)(Af + o1 + k0 + 4);
      float v0[8] = {a00.x, a00.y, a00.z, a00.w, a01.x, a01.y, a01.z, a01.w};
      float v1[8] = {a10.x, a10.y, a10.z, a10.w, a11.x, a11.y, a11.z, a11.w};
      if (stats) {
        float4 g0 = *(const float4*)(gamma + k0 + sc);
        float4 g1 = *(const float4*)(gamma + k0 + sc + 4);
        float4 e0 = *(const float4*)(beta + k0 + sc);
        float4 e1 = *(const float4*)(beta + k0 + sc + 4);
        float gv[8] = {g0.x, g0.y, g0.z, g0.w, g1.x, g1.y, g1.z, g1.w};
        float ev[8] = {e0.x, e0.y, e0.z, e0.w, e1.x, e1.y, e1.z, e1.w};
#pragma unroll
        for (int i = 0; i < 8; i++) {
          v0[i] = (v0[i] - st0.x) * st0.y * gv[i] + ev[i];
          v1[i] = (v1[i] - st1.x) * st1.y * gv[i] + ev[i];
        }
      }
#pragma unroll
      for (int i = 0; i < 8; i++) { ra0[i] = f2s(v0[i]); ra1[i] = f2s(v1[i]); }
    } else {
      ra0 = *(const short8*)(Ab + o0 + k0);
      ra1 = *(const short8*)(Ab + o1 + k0);
      if (stats) {
        float4 g0 = *(const float4*)(gamma + k0 + sc);
        float4 g1 = *(const float4*)(gamma + k0 + sc + 4);
        float4 e0 = *(const float4*)(beta + k0 + sc);
        float4 e1 = *(const float4*)(beta + k0 + sc + 4);
        float gv[8] = {g0.x, g0.y, g0.z, g0.w, g1.x, g1.y, g1.z, g1.w};
        float ev[8] = {e0.x, e0.y, e0.z, e0.w, e1.x, e1.y, e1.z, e1.w};
#pragma unroll
        for (int i = 0; i < 8; i++) {
          ra0[i] = f2s((s2f(ra0[i]) - st0.x) * st0.y * gv[i] + ev[i]);
          ra1[i] = f2s((s2f(ra1[i]) - st1.x) * st1.y * gv[i] + ev[i]);
        }
      }
    }
    short8 b0 = *(const short8*)(Bp0 + k0);
    short8 b1 = *(const short8*)(Bp1 + k0);
    rb0 = b0; rb1 = b1;
  };

  auto STORESET = [&](int p, short8 ra0, short8 ra1, short8 rb0, short8 rb1) {
    *(short8*)&As[p * 4096 + stO]        = ra0;
    *(short8*)&As[p * 4096 + 2048 + stO] = ra1;
    *(short8*)&Bs[p * 4096 + stO]        = rb0;
    *(short8*)&Bs[p * 4096 + 2048 + stO] = rb1;
  };

  auto COMPUTE = [&](int p) {
    short8 af[4], bfr[4];
#pragma unroll
    for (int i = 0; i < 4; i++) {
      int Ra = wm + i * 16 + lr;
      int Rb = wn + i * 16 + lr;
      af[i]  = *(const short8*)&As[p * 4096 + Ra * 32 + (lq ^ ((Ra >> 1) & 3)) * 8];
      bfr[i] = *(const short8*)&Bs[p * 4096 + Rb * 32 + (lq ^ ((Rb >> 1) & 3)) * 8];
    }
#pragma unroll
    for (int i = 0; i < 4; i++)
#pragma unroll
      for (int j = 0; j < 4; j++)
        acc[i][j] = __builtin_amdgcn_mfma_f32_16x16x32_bf16(af[i], bfr[j], acc[i][j], 0, 0, 0);
  };

  // --- software-pipelined K loop: 2-slice reg prefetch, LDS double buffer ---
  short8 pa0, pa1, pb0, pb1, qa0, qa1, qb0, qb1;
  LOADSET(0,  pa0, pa1, pb0, pb1);
  LOADSET(32, qa0, qa1, qb0, qb1);
  STORESET(0, pa0, pa1, pb0, pb1);
  __syncthreads();
  const int nI = K >> 5;  // even, >= 2
  for (int it = 0; it < nI; it += 2) {
    if (it + 2 < nI) LOADSET((it + 2) * 32, pa0, pa1, pb0, pb1);
    COMPUTE(0);
    STORESET(1, qa0, qa1, qb0, qb1);
    __syncthreads();
    if (it + 3 < nI) LOADSET((it + 3) * 32, qa0, qa1, qb0, qb1);
    COMPUTE(1);
    if (it + 2 < nI) STORESET(0, pa0, pa1, pb0, pb1);
    __syncthreads();
  }

  if constexpr (TRANSC) {
    bf16* TC = smem;  // alias: all As/Bs reads are done (final barrier above)
    // C/D layout: col(n) = lane&15, row(m) = (lane>>4)*4 + reg.
#pragma unroll
    for (int i = 0; i < 4; i++) {
      int rloc = wm + i * 16 + lq * 4;
#pragma unroll
      for (int j = 0; j < 4; j++) {
        int cloc = wn + j * 16 + lr;
#pragma unroll
        for (int r = 0; r < 4; r++)
          TC[cloc * 136 + rloc + r] = f2b(acc[i][j][r]);
      }
    }
    __syncthreads();
    long base = (long)n0 * ldc + m0;
#pragma unroll
    for (int p = 0; p < 8; p++) {
      int er = (t >> 4) + p * 16;   // local e row (0..127)
      int mc = (t & 15) * 8;        // local m col
      *(short8*)(C + base + (long)er * ldc + mc) = *(const short8*)&TC[er * 136 + mc];
    }
    return;
  }

#pragma unroll
  for (int i = 0; i < 4; i++) {
    int row0 = m0 + wm + i * 16 + lq * 4;
#pragma unroll
    for (int j = 0; j < 4; j++) {
      int col = n0 + wn + j * 16 + lr;
      if constexpr (ATOM) {
#pragma unroll
        for (int r = 0; r < 4; r++) {
          long idx = (long)(row0 + r) * ldc + col;
          atomicAdd(&Cf[idx], acc[i][j][r]);
        }
      } else {
        float bv = bias ? bias[col] : 0.0f;
#pragma unroll
        for (int r = 0; r < 4; r++) {
          float v = acc[i][j][r] + bv;
          long idx = (long)(row0 + r) * ldc + col;
          if (res) {
            if constexpr (RESF32) v += resf[idx]; else v += b2f(resb[idx]);
          }
          if (act) v = gelu_f(v);
          if constexpr (CFP32) Cf[idx] = v; else C[idx] = f2b(v);
        }
      }
    }
  }
}

// ---------------------------------------------------------------------------
// Tiled transpose fp32 -> bf16: dst[c][r] = (bf16)src[r][c].
// Grid: (Csrc/32, Rsrc/32). Block (32,8).
// ---------------------------------------------------------------------------
__global__ void transpose_f2b(const float* __restrict__ src, bf16* __restrict__ dst,
                              int lsrc, int ldst)
{
  __shared__ bf16 tile[32][33];
  int tx = threadIdx.x, ty = threadIdx.y;
  int c0 = blockIdx.x * 32, r0 = blockIdx.y * 32;
#pragma unroll
  for (int j = 0; j < 4; j++)
    tile[ty + j * 8][tx] = f2b(src[(long)(r0 + ty + j * 8) * lsrc + c0 + tx]);
  __syncthreads();
#pragma unroll
  for (int j = 0; j < 4; j++)
    dst[(long)(c0 + ty + j * 8) * ldst + r0 + tx] = tile[tx][ty + j * 8];
}

// copy x2 chunk row r cols [0,1024) -> G row r cols [4096,5120).
__global__ __launch_bounds__(128) void copy_cols(const bf16* __restrict__ s,
                                                 bf16* __restrict__ d)
{
  int r = blockIdx.x, c = threadIdx.x * 8;
  *(short8*)(d + (long)r * 5120 + 4096 + c) = *(const short8*)(s + (long)r * 1024 + c);
}

// LN stats over D=1024: stats[row] = {mean, rsqrt(var+eps)}. fp32 input.
__global__ __launch_bounds__(256) void ln_stats_f32(
    const float* __restrict__ x, float2* __restrict__ stats)
{
  int row = blockIdx.x, t = threadIdx.x;
  const float* xr = x + (long)row * 1024;
  float4 a = *(const float4*)(xr + t * 4);
  float s = a.x + a.y + a.z + a.w;
  float q = a.x * a.x + a.y * a.y + a.z * a.z + a.w * a.w;
  for (int o = 32; o > 0; o >>= 1) { s += __shfl_down(s, o); q += __shfl_down(q, o); }
  __shared__ float sm[8];
  if ((t & 63) == 0) { sm[t >> 6] = s; sm[4 + (t >> 6)] = q; }
  __syncthreads();
  if (t == 0) {
    s = sm[0] + sm[1] + sm[2] + sm[3];
    q = sm[4] + sm[5] + sm[6] + sm[7];
    float mean = s * (1.0f / 1024.0f);
    float var  = q * (1.0f / 1024.0f) - mean * mean;
    stats[row] = make_float2(mean, rsqrtf(var + 1e-5f));
  }
}

// xln[i] = bf16((x[i]-mu)*rstd*g+b), 8 elems/thread (all within one row).
__global__ __launch_bounds__(256) void ln_apply(
    const float* __restrict__ x, const float2* __restrict__ stats,
    const float* __restrict__ g, const float* __restrict__ b,
    bf16* __restrict__ out)
{
  long i = ((long)blockIdx.x * 256 + threadIdx.x) * 8;
  int row = (int)(i >> 10), col = (int)(i & 1023);
  float2 st = stats[row];
  float4 a0 = *(const float4*)(x + i);
  float4 a1 = *(const float4*)(x + i + 4);
  float4 g0 = *(const float4*)(g + col);
  float4 g1 = *(const float4*)(g + col + 4);
  float4 b0 = *(const float4*)(b + col);
  float4 b1 = *(const float4*)(b + col + 4);
  float av[8] = {a0.x, a0.y, a0.z, a0.w, a1.x, a1.y, a1.z, a1.w};
  float gv[8] = {g0.x, g0.y, g0.z, g0.w, g1.x, g1.y, g1.z, g1.w};
  float bv[8] = {b0.x, b0.y, b0.z, b0.w, b1.x, b1.y, b1.z, b1.w};
  short8 o;
#pragma unroll
  for (int j = 0; j < 8; j++)
    o[j] = f2s((av[j] - st.x) * st.y * gv[j] + bv[j]);
  *(short8*)(out + i) = o;
}

// LN stats, bf16 input.
__global__ __launch_bounds__(256) void ln_stats_b16(
    const bf16* __restrict__ x, float2* __restrict__ stats)
{
  int row = blockIdx.x, t = threadIdx.x;
  const bf16* xr = x + (long)row * 1024;
  float v[4];
#pragma unroll
  for (int i = 0; i < 4; i++) v[i] = b2f(xr[t * 4 + i]);
  float s = v[0] + v[1] + v[2] + v[3];
  float q = v[0] * v[0] + v[1] * v[1] + v[2] * v[2] + v[3] * v[3];
  for (int o = 32; o > 0; o >>= 1) { s += __shfl_down(s, o); q += __shfl_down(q, o); }
  __shared__ float sm[8];
  if ((t & 63) == 0) { sm[t >> 6] = s; sm[4 + (t >> 6)] = q; }
  __syncthreads();
  if (t == 0) {
    s = sm[0] + sm[1] + sm[2] + sm[3];
    q = sm[4] + sm[5] + sm[6] + sm[7];
    float mean = s * (1.0f / 1024.0f);
    float var  = q * (1.0f / 1024.0f) - mean * mean;
    stats[row] = make_float2(mean, rsqrtf(var + 1e-5f));
  }
}

// softmax over 256 contiguous elems per row (q~, per-head). In place, bf16.
__global__ __launch_bounds__(256) void qsoftmax256(bf16* __restrict__ q)
{
  long idx = (long)blockIdx.x * 256 + threadIdx.x;
  int t = threadIdx.x;
  float v = expf(0.25f * b2f(q[idx]));
  float s = v;
  for (int o = 32; o > 0; o >>= 1) s += __shfl_down(s, o);
  __shared__ float sm[4];
  if ((t & 63) == 0) sm[t >> 6] = s;
  __syncthreads();
  float tot = sm[0] + sm[1] + sm[2] + sm[3];
  q[idx] = f2b(v / tot);
}

// k softmax on fused KV buffer [4b][512e][4096n]: rows e<256 of each batch
// are k~; row-softmax exp(0.25x)/rowsum in place.
__global__ __launch_bounds__(256) void ksoftmaxKV(bf16* __restrict__ kv)
{
  int b = blockIdx.x >> 8, e = blockIdx.x & 255;
  long base = ((long)b * 512 + e) * 4096;
  int t = threadIdx.x;
  float loc[16];
  float s = 0.0f;
#pragma unroll
  for (int i = 0; i < 16; i++) {
    loc[i] = expf(0.25f * b2f(kv[base + t + i * 256]));
    s += loc[i];
  }
  for (int o = 32; o > 0; o >>= 1) s += __shfl_down(s, o);
  __shared__ float sm[4];
  if ((t & 63) == 0) sm[t >> 6] = s;
  __syncthreads();
  float inv = 1.0f / (sm[0] + sm[1] + sm[2] + sm[3]);
#pragma unroll
  for (int i = 0; i < 16; i++)
    kv[base + t + i * 256] = f2b(loc[i] * inv);
}

// ctx reduce: CTX[i] = sum_kc G[kc*262144 + i], i in [0, 262144).
__global__ __launch_bounds__(256) void reduce_ctx(
    const bf16* __restrict__ G, bf16* __restrict__ CTX)
{
  long i = (long)blockIdx.x * 256 + threadIdx.x;
  float s = 0.0f;
#pragma unroll
  for (int kc = 0; kc < 8; kc++) s += b2f(G[kc * 262144 + i]);
  CTX[i] = f2b(s);
}

// OB[n] = sum_k b2[k] * wdt[n][k] + bd[n]   (n = blockIdx.x; wdt row stride ld)
__global__ __launch_bounds__(256) void out_bias(
    const float* __restrict__ b2, const bf16* __restrict__ wdt, int ld,
    const float* __restrict__ bd, float* __restrict__ OB)
{
  int n = blockIdx.x, t = threadIdx.x;
  const bf16* wr = wdt + (long)n * ld;
  float s = 0.0f;
#pragma unroll
  for (int i = 0; i < 4; i++) {
    int k = t * 4 + i;
    s += b2[k] * b2f(wr[k]);
  }
  for (int o = 32; o > 0; o >>= 1) s += __shfl_down(s, o);
  __shared__ float sm[4];
  if ((t & 63) == 0) sm[t >> 6] = s;
  __syncthreads();
  if (t == 0) OB[n] = sm[0] + sm[1] + sm[2] + sm[3] + bd[n];
}

// out[r][c] = b[c] over 1024x1024 fp32 (seed for atomic split-K GEMMs)
__global__ __launch_bounds__(256) void bias_bcast(
    const float* __restrict__ b, float* __restrict__ out)
{
  long i = ((long)blockIdx.x * 256 + threadIdx.x) * 4;
  *(float4*)(out + i) = *(const float4*)(b + (int)(i & 1023));
}

extern "C" void kernel_launch(void* const* d_in, const int* in_sizes, int n_in,
                              void* d_out, int out_size, void* d_ws, size_t ws_size,
                              hipStream_t stream) {
  const float* x    = (const float*)d_in[0];
  const float* ln1g = (const float*)d_in[1];
  const float* ln1b = (const float*)d_in[2];
  const float* wq   = (const float*)d_in[3];
  const float* wk   = (const float*)d_in[4];
  const float* wv   = (const float*)d_in[5];
  const float* wo   = (const float*)d_in[6];
  const float* bo   = (const float*)d_in[7];
  const float* ln2g = (const float*)d_in[8];
  const float* ln2b = (const float*)d_in[9];
  const float* wff1 = (const float*)d_in[10];
  const float* bff1 = (const float*)d_in[11];
  const float* wff2 = (const float*)d_in[12];
  const float* bff2 = (const float*)d_in[13];
  const float* wd   = (const float*)d_in[14];
  const float* bd   = (const float*)d_in[15];

  // d_out (64MB fp32) as scratch: first half xln (bf16 LN1(x)), second x2.
  bf16* xln = (bf16*)d_out;                           // 16384x1024 bf16
  bf16* x2  = (bf16*)d_out + (size_t)16384 * 1024;    // 16384x1024 bf16
  float* outf = (float*)d_out;

  char* wsp = (char*)d_ws;
  size_t off = 0;
  auto alloc = [&](size_t bytes) -> void* {
    void* p = wsp + off; off += (bytes + 255) & ~(size_t)255; return p;
  };
  bf16*   S1  = (bf16*)alloc((size_t)8 * 1024 * 1024);    // KV lo | q_all | wff1T
  bf16*   S2  = (bf16*)alloc((size_t)10 * 1024 * 1024);   // KV hi | attn_h | WB
  bf16*   G   = (bf16*)alloc((size_t)10 * 1024 * 1024);   // ctx partials | [g|x2_R]
  bf16*   CTX = (bf16*)alloc((size_t)4 * 256 * 256 * 2);  // ctx_h | OB overlay
  bf16*   W1  = (bf16*)alloc((size_t)1024 * 256 * 2);     // wq/wo slice (BT form)
  float2* st1 = (float2*)alloc((size_t)16384 * 8);
  float2* st2 = (float2*)alloc((size_t)16384 * 8);
  bf16*   KV  = S1;                          // [4b][512e][4096n] = 16MB (S1+S2)
  bf16*   W1kv = G + (size_t)9 * 512 * 1024; // G bytes [9MB,10MB): [512][1024]
  bf16*   WB  = S2;                          // FFN: [1024][5120] = [WCD^T|wd^T]
  float*  OB  = (float*)CTX;                 // 4KB, CTX dead during FFN
  // total ws = 30,670,848 B — identical to the proven baseline footprint.

  const long SA  = (long)4096 * 1024;  // per-batch xln row stride (elements)
  const long PKV = (long)512 * 4096;   // per-batch KV [e][n] stride
  dim3 tb(32, 8);
  const bf16* nb = nullptr;

  // ---- LN1 stats + xln = bf16(LN1(x)) ----
  ln_stats_f32<<<16384, 256, 0, stream>>>(x, st1);
  ln_apply<<<8192, 256, 0, stream>>>(x, st1, ln1g, ln1b, xln);

  // ---- attention, per head; x2 accumulates into second half of d_out ----
  for (int h = 0; h < 4; h++) {
    // KV = (xln @ [wk_h|wv_h])^T -> [4b][512e][4096n]; k rows then v rows.
    transpose_f2b<<<dim3(8, 32), tb, 0, stream>>>(wk + h * 256, W1kv, 1024, 1024);
    transpose_f2b<<<dim3(8, 32), tb, 0, stream>>>(wv + h * 256, W1kv + 256 * 1024, 1024, 1024);
    gemm_bt<1, 0, 0, 0><<<dim3(4, 32, 4), 256, 0, stream>>>(xln, W1kv, KV,
        1024, 1024, 1024, 4096, 2, 0, SA, 0, 0, 0, PKV,
        nullptr, nb, 0, nullptr, nullptr, nullptr);
    ksoftmaxKV<<<1024, 256, 0, stream>>>(KV);

    // ctx partials: G[kc][b][e][d] = sum_{n in kc} v[e][n] * k~[d][n]
    gemm_bt<0, 0, 0, 0><<<dim3(2, 2, 32), 256, 0, stream>>>(KV + (long)256 * 4096, KV, G,
        512, 4096, 4096, 256, 3, PKV, 512, PKV, 512, 65536, 262144,
        nullptr, nb, 0, nullptr, nullptr, nullptr);
    reduce_ctx<<<1024, 256, 0, stream>>>(G, CTX);

    // q_h = xln@wq[:,h] -> S1 [4b][4096][256]; softmax over dh (KV k dead)
    transpose_f2b<<<dim3(8, 32), tb, 0, stream>>>(wq + h * 256, W1, 1024, 1024);
    gemm_bt<0, 0, 0, 0><<<dim3(2, 32, 4), 256, 0, stream>>>(xln, W1, S1,
        1024, 1024, 1024, 256, 2, 0, SA, 0, 0, 0, (long)4096 * 256,
        nullptr, nb, 0, nullptr, nullptr, nullptr);
    qsoftmax256<<<16384, 256, 0, stream>>>(S1);

    // attn_h[n][e] = sum_d q~[n][d] * ctx[e][d] -> S2 [4b][4096][256]
    gemm_bt<0, 0, 0, 0><<<dim3(2, 32, 4), 256, 0, stream>>>(S1, CTX, S2,
        256, 256, 256, 256, 2, 0, (long)4096 * 256, 0, 65536, 0, (long)4096 * 256,
        nullptr, nb, 0, nullptr, nullptr, nullptr);

    // x2 += attn_h @ wo[h rows]  (h==0 seeds x + bo, x read as fp32)
    transpose_f2b<<<dim3(32, 8), tb, 0, stream>>>(wo + (size_t)h * 256 * 1024, W1, 1024, 256);
    if (h == 0)
      gemm_bt<0, 0, 0, 0, 1><<<dim3(8, 128, 1), 256, 0, stream>>>(S2, W1, x2,
          256, 256, 256, 1024, 2, 0, 0, 0, 0, 0, 0,
          bo, (const bf16*)x, 0, nullptr, nullptr, nullptr);
    else
      gemm_bt<0, 0, 0, 0, 0><<<dim3(8, 128, 1), 256, 0, stream>>>(S2, W1, x2,
          256, 256, 256, 1024, 2, 0, 0, 0, 0, 0, 0,
          nullptr, x2, 0, nullptr, nullptr, nullptr);
  }

  // ---- FFN + trailing dense: out = [g|x2_R] @ [WCD^T|wd^T]^T + OB ----
  ln_stats_b16<<<16384, 256, 0, stream>>>(x2, st2);
  transpose_f2b<<<dim3(128, 32), tb, 0, stream>>>(wff1, S1, 4096, 1024);  // S1 = wff1T
  // WB cols [4096:5120) = wd^T  (row stride 5120)
  transpose_f2b<<<dim3(32, 32), tb, 0, stream>>>(wd, WB + 4096, 1024, 5120);
  // WB cols [0:4096) = WCD^T = (wff2@wd)^T; B operand = wd^T slice of WB.
  gemm_bt<1, 1, 0, 0><<<dim3(8, 32, 1), 256, 0, stream>>>(wff2, WB + 4096, WB,
      1024, 1024, 5120, 5120, 0, 0, 0, 0, 0, 0, 0,
      nullptr, nb, 0, nullptr, nullptr, nullptr);
  // OB[n] = b_ff2 @ wd + b_d
  out_bias<<<1024, 256, 0, stream>>>(bff2, WB + 4096, 5120, bd, OB);

  for (int R = 0; R < 16; R++) {
    const bf16* xr = x2 + (size_t)R * 1024 * 1024;  // x2 rows (bf16)
    // G cols [4096:5120) = x2_R  (also rescues chunk 15 from its own out-write)
    copy_cols<<<1024, 128, 0, stream>>>(xr, G);
    // G cols [0:4096) = gelu(LN2(x2_R) @ wff1T + b1)
    gemm_bt<0, 0, 0, 0><<<dim3(32, 8, 1), 256, 0, stream>>>(xr, S1, G,
        1024, 1024, 1024, 5120, 2, 0, 0, 0, 0, 0, 0,
        bff1, nb, 1, st2 + R * 1024, ln2g, ln2b);
    // out_R = OB (seed); after gemm1(R) — chunk 15's out-write covers x2 rows
    // gemm1(15) reads.
    bias_bcast<<<1024, 256, 0, stream>>>(OB, outf + (size_t)R * 1024 * 1024);
    // out_R += [g|x2_R] @ WB^T  (split-K: z=8 slices of K=640 -> 512 blocks)
    gemm_bt<0, 0, 1, 1><<<dim3(8, 8, 8), 256, 0, stream>>>(G, WB,
        outf + (size_t)R * 1024 * 1024,
        640, 5120, 5120, 1024, 3, 0, 640, 0, 640, 0, 0,
        nullptr, nb, 0, nullptr, nullptr, nullptr);
  }
}

// Round 5
// 1969.878 us; speedup vs baseline: 1.8692x; 1.1435x over previous
//
#include <hip/hip_runtime.h>
#include <hip/hip_bf16.h>

// LinearformerBlock on MI355X (gfx950). I/O is FP32; internals bf16 MFMA with
// fp32 accumulation. B=4,N=4096,D=1024,H=4,DH=256,FF=4096.
//
// ws = 30,670,848 B — EXACTLY the proven baseline footprint.
//
// d_out (64MB fp32) doubles as scratch: first half = xln (bf16 LN1(x)),
// second half = x2 (bf16). Final dense writes fp32 rows forward-order;
// out chunk R clobbers x2 rows [2048R-16384, 2048R-14336) — always below
// later chunks' first needed row. Chunk R's own x2 data is rescued by
// copy_cols into G cols [4096:5120) before any out-write of chunk R.
//
// r6: FFN algebra out = x2@wd + g@(wff2@wd) + (b2@wd+bd). 3682 -> 2904.
// r7: K-concat FFN epilogue + LN1 hoist (xln). 2904 -> 2468.
// r8: LDS XOR-swizzle (bank conflicts -> 0) + dbuf pipeline + fused KV. -> 2253.
// r9 (this round):
//  (a) out-GEMM z=8 -> z=4 (K=1280): halves atomic RMW traffic (36.6 -> ~20MB
//      WRITE per dispatch), the top cost class (989us total).
//  (b) attention algebra: sum_h (q~_h@ctx_h)@wo_h == q~_all @ CW with
//      CW[(h,d)][c] = sum_e ctx_h[d][e] wo_h[e][c]. Per head: only KV + ctx
//      (operand-swapped to emit context[d][e], 16 seq-chunks -> 256 blocks).
//      Once: CWT = f(woT, ctxT) (256 blocks). Per batch-pair: fused q-GEMM
//      (all heads, K=1024, 512 blocks), qsoftmax, ONE x2-GEMM (K=1024,
//      512 blocks, res=x fp32, bias=bo). Deletes 4 attn-GEMMs, 4 wo-GEMMs
//      (and their 4x RMW of the 32MB x2), 8 per-head transposes.
//      CTXT[4b][4h][256d][256e] = 2MB in S2 tail; woT/CWT in G; q~ pair
//      buffer (16MB) reuses dead KV space (S1+S2[0:8MB)).

typedef __hip_bfloat16 bf16;
typedef __attribute__((ext_vector_type(8))) short short8;
typedef __attribute__((ext_vector_type(4))) float floatx4;

__device__ __forceinline__ float b2f(bf16 x) { return __bfloat162float(x); }
__device__ __forceinline__ bf16 f2b(float x) { return __float2bfloat16(x); }
__device__ __forceinline__ float s2f(short s) {
  unsigned int u = ((unsigned int)(unsigned short)s) << 16;
  return __uint_as_float(u);
}
__device__ __forceinline__ short f2s(float f) {
  bf16 h = __float2bfloat16(f);
  return *reinterpret_cast<short*>(&h);
}
__device__ __forceinline__ float gelu_f(float x) {
  float u = 0.7978845608028654f * (x + 0.044715f * x * x * x);
  return 0.5f * x * (1.0f + tanhf(u));
}

// ---------------------------------------------------------------------------
// GEMM: C[m][n] = sum_k A'[m][k] * BT[n][k]   (A' = LN(A) if stats!=null)
// 128x128 tile, BK=32, 4 waves x (4x4) 16x16x32 bf16 MFMA.
// K must be a multiple of 64 and >= 64.
// LDS: double-buffered As/Bs with XOR-swizzled 16B slots (conflict-free).
// K-loop: 2-slice register prefetch, one barrier per slice.
// AFP32: A operand fp32. CFP32: C fp32. TRANSC: C transposed (bf16, via LDS).
// ATOM: atomicAdd into fp32 C (split-K). RESF32: residual read as fp32.
// ---------------------------------------------------------------------------
template <int TRANSC, int AFP32, int CFP32, int ATOM, int RESF32 = 0>
__global__ __launch_bounds__(256) void gemm_bt(
    const void* __restrict__ Aop, const bf16* __restrict__ BT, void* Cv,
    int K, int lda, int ldb, int ldc, int zshift,
    long saA, long shA, long saB, long shB, long saC, long shC,
    const float* __restrict__ bias, const bf16* res, int act,
    const float2* stats, const float* __restrict__ gamma,
    const float* __restrict__ beta)
{
  int z = blockIdx.z;
  int zb = z >> zshift, zh = z & ((1 << zshift) - 1);
  long offA = (long)zb * saA + (long)zh * shA;
  long offC = (long)zb * saC + (long)zh * shC;
  const float* Af = (const float*)Aop + offA;
  const bf16*  Ab = (const bf16*)Aop + offA;
  BT += (long)zb * saB + (long)zh * shB;
  bf16*  C  = (bf16*)Cv + offC;
  float* Cf = (float*)Cv + offC;
  const bf16*  resb = res ? res + offC : nullptr;
  const float* resf = res ? (const float*)res + offC : nullptr;
  if (stats) stats += offA / lda;

  // smem: As = [2][128*32] at 0, Bs = [2][128*32] at 8192. TRANSC epilogue
  // aliases the whole region as TC[128*136] (safe: used after final barrier).
  __shared__ bf16 smem[TRANSC ? 128 * 136 : 16384];
  bf16* As = smem;
  bf16* Bs = smem + 8192;

  const int t = threadIdx.x;
  const int w = t >> 6, l = t & 63;
  const int m0 = blockIdx.y * 128, n0 = blockIdx.x * 128;
  const int wm = (w >> 1) * 64, wn = (w & 1) * 64;
  const int lr = l & 15, lq = l >> 4;

  floatx4 acc[4][4] = {};

  const int sr = t >> 2;        // staging row within half-tile (0..63)
  const int sc = (t & 3) * 8;   // staging col (0,8,16,24)
  // swizzled 16B-slot store offset: slot s -> s ^ ((row>>1)&3).
  const int stO = sr * 32 + (((t & 3) ^ ((sr >> 1) & 3))) * 8;
  const int rowA0 = m0 + sr, rowA1 = m0 + 64 + sr;
  const long o0 = (long)rowA0 * lda + sc;
  const long o1 = (long)rowA1 * lda + sc;

  const bf16* Bp0 = BT + (long)(n0 + sr) * ldb + sc;
  const bf16* Bp1 = BT + (long)(n0 + 64 + sr) * ldb + sc;

  float2 st0, st1;
  if (stats) { st0 = stats[rowA0]; st1 = stats[rowA1]; }

  auto LOADSET = [&](int k0, short8& ra0, short8& ra1, short8& rb0, short8& rb1) {
    if constexpr (AFP32) {
      float4 a00 = *(const float4*)(Af + o0 + k0);
      float4 a01 = *(const float4*)(Af + o0 + k0 + 4);
      float4 a10 = *(const float4*)(Af + o1 + k0);
      float4 a11 = *(const float4*)(Af + o1 + k0 + 4);
      float v0[8] = {a00.x, a00.y, a00.z, a00.w, a01.x, a01.y, a01.z, a01.w};
      float v1[8] = {a10.x, a10.y, a10.z, a10.w, a11.x, a11.y, a11.z, a11.w};
      if (stats) {
        float4 g0 = *(const float4*)(gamma + k0 + sc);
        float4 g1 = *(const float4*)(gamma + k0 + sc + 4);
        float4 e0 = *(const float4*)(beta + k0 + sc);
        float4 e1 = *(const float4*)(beta + k0 + sc + 4);
        float gv[8] = {g0.x, g0.y, g0.z, g0.w, g1.x, g1.y, g1.z, g1.w};
        float ev[8] = {e0.x, e0.y, e0.z, e0.w, e1.x, e1.y, e1.z, e1.w};
#pragma unroll
        for (int i = 0; i < 8; i++) {
          v0[i] = (v0[i] - st0.x) * st0.y * gv[i] + ev[i];
          v1[i] = (v1[i] - st1.x) * st1.y * gv[i] + ev[i];
        }
      }
#pragma unroll
      for (int i = 0; i < 8; i++) { ra0[i] = f2s(v0[i]); ra1[i] = f2s(v1[i]); }
    } else {
      ra0 = *(const short8*)(Ab + o0 + k0);
      ra1 = *(const short8*)(Ab + o1 + k0);
      if (stats) {
        float4 g0 = *(const float4*)(gamma + k0 + sc);
        float4 g1 = *(const float4*)(gamma + k0 + sc + 4);
        float4 e0 = *(const float4*)(beta + k0 + sc);
        float4 e1 = *(const float4*)(beta + k0 + sc + 4);
        float gv[8] = {g0.x, g0.y, g0.z, g0.w, g1.x, g1.y, g1.z, g1.w};
        float ev[8] = {e0.x, e0.y, e0.z, e0.w, e1.x, e1.y, e1.z, e1.w};
#pragma unroll
        for (int i = 0; i < 8; i++) {
          ra0[i] = f2s((s2f(ra0[i]) - st0.x) * st0.y * gv[i] + ev[i]);
          ra1[i] = f2s((s2f(ra1[i]) - st1.x) * st1.y * gv[i] + ev[i]);
        }
      }
    }
    short8 b0 = *(const short8*)(Bp0 + k0);
    short8 b1 = *(const short8*)(Bp1 + k0);
    rb0 = b0; rb1 = b1;
  };

  auto STORESET = [&](int p, short8 ra0, short8 ra1, short8 rb0, short8 rb1) {
    *(short8*)&As[p * 4096 + stO]        = ra0;
    *(short8*)&As[p * 4096 + 2048 + stO] = ra1;
    *(short8*)&Bs[p * 4096 + stO]        = rb0;
    *(short8*)&Bs[p * 4096 + 2048 + stO] = rb1;
  };

  auto COMPUTE = [&](int p) {
    short8 af[4], bfr[4];
#pragma unroll
    for (int i = 0; i < 4; i++) {
      int Ra = wm + i * 16 + lr;
      int Rb = wn + i * 16 + lr;
      af[i]  = *(const short8*)&As[p * 4096 + Ra * 32 + (lq ^ ((Ra >> 1) & 3)) * 8];
      bfr[i] = *(const short8*)&Bs[p * 4096 + Rb * 32 + (lq ^ ((Rb >> 1) & 3)) * 8];
    }
#pragma unroll
    for (int i = 0; i < 4; i++)
#pragma unroll
      for (int j = 0; j < 4; j++)
        acc[i][j] = __builtin_amdgcn_mfma_f32_16x16x32_bf16(af[i], bfr[j], acc[i][j], 0, 0, 0);
  };

  // --- software-pipelined K loop: 2-slice reg prefetch, LDS double buffer ---
  short8 pa0, pa1, pb0, pb1, qa0, qa1, qb0, qb1;
  LOADSET(0,  pa0, pa1, pb0, pb1);
  LOADSET(32, qa0, qa1, qb0, qb1);
  STORESET(0, pa0, pa1, pb0, pb1);
  __syncthreads();
  const int nI = K >> 5;  // even, >= 2
  for (int it = 0; it < nI; it += 2) {
    if (it + 2 < nI) LOADSET((it + 2) * 32, pa0, pa1, pb0, pb1);
    COMPUTE(0);
    STORESET(1, qa0, qa1, qb0, qb1);
    __syncthreads();
    if (it + 3 < nI) LOADSET((it + 3) * 32, qa0, qa1, qb0, qb1);
    COMPUTE(1);
    if (it + 2 < nI) STORESET(0, pa0, pa1, pb0, pb1);
    __syncthreads();
  }

  if constexpr (TRANSC) {
    bf16* TC = smem;  // alias: all As/Bs reads are done (final barrier above)
    // C/D layout: col(n) = lane&15, row(m) = (lane>>4)*4 + reg.
#pragma unroll
    for (int i = 0; i < 4; i++) {
      int rloc = wm + i * 16 + lq * 4;
#pragma unroll
      for (int j = 0; j < 4; j++) {
        int cloc = wn + j * 16 + lr;
#pragma unroll
        for (int r = 0; r < 4; r++)
          TC[cloc * 136 + rloc + r] = f2b(acc[i][j][r]);
      }
    }
    __syncthreads();
    long base = (long)n0 * ldc + m0;
#pragma unroll
    for (int p = 0; p < 8; p++) {
      int er = (t >> 4) + p * 16;   // local e row (0..127)
      int mc = (t & 15) * 8;        // local m col
      *(short8*)(C + base + (long)er * ldc + mc) = *(const short8*)&TC[er * 136 + mc];
    }
    return;
  }

#pragma unroll
  for (int i = 0; i < 4; i++) {
    int row0 = m0 + wm + i * 16 + lq * 4;
#pragma unroll
    for (int j = 0; j < 4; j++) {
      int col = n0 + wn + j * 16 + lr;
      if constexpr (ATOM) {
#pragma unroll
        for (int r = 0; r < 4; r++) {
          long idx = (long)(row0 + r) * ldc + col;
          atomicAdd(&Cf[idx], acc[i][j][r]);
        }
      } else {
        float bv = bias ? bias[col] : 0.0f;
#pragma unroll
        for (int r = 0; r < 4; r++) {
          float v = acc[i][j][r] + bv;
          long idx = (long)(row0 + r) * ldc + col;
          if (res) {
            if constexpr (RESF32) v += resf[idx]; else v += b2f(resb[idx]);
          }
          if (act) v = gelu_f(v);
          if constexpr (CFP32) Cf[idx] = v; else C[idx] = f2b(v);
        }
      }
    }
  }
}

// ---------------------------------------------------------------------------
// Tiled transpose fp32 -> bf16: dst[c][r] = (bf16)src[r][c].
// Grid: (Csrc/32, Rsrc/32). Block (32,8).
// ---------------------------------------------------------------------------
__global__ void transpose_f2b(const float* __restrict__ src, bf16* __restrict__ dst,
                              int lsrc, int ldst)
{
  __shared__ bf16 tile[32][33];
  int tx = threadIdx.x, ty = threadIdx.y;
  int c0 = blockIdx.x * 32, r0 = blockIdx.y * 32;
#pragma unroll
  for (int j = 0; j < 4; j++)
    tile[ty + j * 8][tx] = f2b(src[(long)(r0 + ty + j * 8) * lsrc + c0 + tx]);
  __syncthreads();
#pragma unroll
  for (int j = 0; j < 4; j++)
    dst[(long)(c0 + ty + j * 8) * ldst + r0 + tx] = tile[tx][ty + j * 8];
}

// copy x2 chunk row r cols [0,1024) -> G row r cols [4096,5120).
__global__ __launch_bounds__(128) void copy_cols(const bf16* __restrict__ s,
                                                 bf16* __restrict__ d)
{
  int r = blockIdx.x, c = threadIdx.x * 8;
  *(short8*)(d + (long)r * 5120 + 4096 + c) = *(const short8*)(s + (long)r * 1024 + c);
}

// LN stats over D=1024: stats[row] = {mean, rsqrt(var+eps)}. fp32 input.
__global__ __launch_bounds__(256) void ln_stats_f32(
    const float* __restrict__ x, float2* __restrict__ stats)
{
  int row = blockIdx.x, t = threadIdx.x;
  const float* xr = x + (long)row * 1024;
  float4 a = *(const float4*)(xr + t * 4);
  float s = a.x + a.y + a.z + a.w;
  float q = a.x * a.x + a.y * a.y + a.z * a.z + a.w * a.w;
  for (int o = 32; o > 0; o >>= 1) { s += __shfl_down(s, o); q += __shfl_down(q, o); }
  __shared__ float sm[8];
  if ((t & 63) == 0) { sm[t >> 6] = s; sm[4 + (t >> 6)] = q; }
  __syncthreads();
  if (t == 0) {
    s = sm[0] + sm[1] + sm[2] + sm[3];
    q = sm[4] + sm[5] + sm[6] + sm[7];
    float mean = s * (1.0f / 1024.0f);
    float var  = q * (1.0f / 1024.0f) - mean * mean;
    stats[row] = make_float2(mean, rsqrtf(var + 1e-5f));
  }
}

// xln[i] = bf16((x[i]-mu)*rstd*g+b), 8 elems/thread (all within one row).
__global__ __launch_bounds__(256) void ln_apply(
    const float* __restrict__ x, const float2* __restrict__ stats,
    const float* __restrict__ g, const float* __restrict__ b,
    bf16* __restrict__ out)
{
  long i = ((long)blockIdx.x * 256 + threadIdx.x) * 8;
  int row = (int)(i >> 10), col = (int)(i & 1023);
  float2 st = stats[row];
  float4 a0 = *(const float4*)(x + i);
  float4 a1 = *(const float4*)(x + i + 4);
  float4 g0 = *(const float4*)(g + col);
  float4 g1 = *(const float4*)(g + col + 4);
  float4 b0 = *(const float4*)(b + col);
  float4 b1 = *(const float4*)(b + col + 4);
  float av[8] = {a0.x, a0.y, a0.z, a0.w, a1.x, a1.y, a1.z, a1.w};
  float gv[8] = {g0.x, g0.y, g0.z, g0.w, g1.x, g1.y, g1.z, g1.w};
  float bv[8] = {b0.x, b0.y, b0.z, b0.w, b1.x, b1.y, b1.z, b1.w};
  short8 o;
#pragma unroll
  for (int j = 0; j < 8; j++)
    o[j] = f2s((av[j] - st.x) * st.y * gv[j] + bv[j]);
  *(short8*)(out + i) = o;
}

// LN stats, bf16 input.
__global__ __launch_bounds__(256) void ln_stats_b16(
    const bf16* __restrict__ x, float2* __restrict__ stats)
{
  int row = blockIdx.x, t = threadIdx.x;
  const bf16* xr = x + (long)row * 1024;
  float v[4];
#pragma unroll
  for (int i = 0; i < 4; i++) v[i] = b2f(xr[t * 4 + i]);
  float s = v[0] + v[1] + v[2] + v[3];
  float q = v[0] * v[0] + v[1] * v[1] + v[2] * v[2] + v[3] * v[3];
  for (int o = 32; o > 0; o >>= 1) { s += __shfl_down(s, o); q += __shfl_down(q, o); }
  __shared__ float sm[8];
  if ((t & 63) == 0) { sm[t >> 6] = s; sm[4 + (t >> 6)] = q; }
  __syncthreads();
  if (t == 0) {
    s = sm[0] + sm[1] + sm[2] + sm[3];
    q = sm[4] + sm[5] + sm[6] + sm[7];
    float mean = s * (1.0f / 1024.0f);
    float var  = q * (1.0f / 1024.0f) - mean * mean;
    stats[row] = make_float2(mean, rsqrtf(var + 1e-5f));
  }
}

// softmax over 256 contiguous elems per row (q~, per-head seg). In place, bf16.
__global__ __launch_bounds__(256) void qsoftmax256(bf16* __restrict__ q)
{
  long idx = (long)blockIdx.x * 256 + threadIdx.x;
  int t = threadIdx.x;
  float v = expf(0.25f * b2f(q[idx]));
  float s = v;
  for (int o = 32; o > 0; o >>= 1) s += __shfl_down(s, o);
  __shared__ float sm[4];
  if ((t & 63) == 0) sm[t >> 6] = s;
  __syncthreads();
  float tot = sm[0] + sm[1] + sm[2] + sm[3];
  q[idx] = f2b(v / tot);
}

// k softmax on fused KV buffer [4b][512e][4096n]: rows e<256 of each batch
// are k~; row-softmax exp(0.25x)/rowsum in place.
__global__ __launch_bounds__(256) void ksoftmaxKV(bf16* __restrict__ kv)
{
  int b = blockIdx.x >> 8, e = blockIdx.x & 255;
  long base = ((long)b * 512 + e) * 4096;
  int t = threadIdx.x;
  float loc[16];
  float s = 0.0f;
#pragma unroll
  for (int i = 0; i < 16; i++) {
    loc[i] = expf(0.25f * b2f(kv[base + t + i * 256]));
    s += loc[i];
  }
  for (int o = 32; o > 0; o >>= 1) s += __shfl_down(s, o);
  __shared__ float sm[4];
  if ((t & 63) == 0) sm[t >> 6] = s;
  __syncthreads();
  float inv = 1.0f / (sm[0] + sm[1] + sm[2] + sm[3]);
#pragma unroll
  for (int i = 0; i < 16; i++)
    kv[base + t + i * 256] = f2b(loc[i] * inv);
}

// ctx reduce: dst[b*262144 + j] = sum_{kc<16} G[kc*262144 + b*65536 + j].
// dst base is CTXT + h*65536 (head-interleaved [b][h][256d][256e]).
__global__ __launch_bounds__(256) void reduce_ctx(
    const bf16* __restrict__ G, bf16* __restrict__ dst)
{
  long i = (long)blockIdx.x * 256 + threadIdx.x;  // [0, 262144)
  float s = 0.0f;
#pragma unroll
  for (int kc = 0; kc < 16; kc++) s += b2f(G[kc * 262144 + i]);
  dst[(i >> 16) * 262144 + (i & 65535)] = f2b(s);
}

// OB[n] = sum_k b2[k] * wdt[n][k] + bd[n]   (n = blockIdx.x; wdt row stride ld)
__global__ __launch_bounds__(256) void out_bias(
    const float* __restrict__ b2, const bf16* __restrict__ wdt, int ld,
    const float* __restrict__ bd, float* __restrict__ OB)
{
  int n = blockIdx.x, t = threadIdx.x;
  const bf16* wr = wdt + (long)n * ld;
  float s = 0.0f;
#pragma unroll
  for (int i = 0; i < 4; i++) {
    int k = t * 4 + i;
    s += b2[k] * b2f(wr[k]);
  }
  for (int o = 32; o > 0; o >>= 1) s += __shfl_down(s, o);
  __shared__ float sm[4];
  if ((t & 63) == 0) sm[t >> 6] = s;
  __syncthreads();
  if (t == 0) OB[n] = sm[0] + sm[1] + sm[2] + sm[3] + bd[n];
}

// out[r][c] = b[c] over 1024x1024 fp32 (seed for atomic split-K GEMMs)
__global__ __launch_bounds__(256) void bias_bcast(
    const float* __restrict__ b, float* __restrict__ out)
{
  long i = ((long)blockIdx.x * 256 + threadIdx.x) * 4;
  *(float4*)(out + i) = *(const float4*)(b + (int)(i & 1023));
}

extern "C" void kernel_launch(void* const* d_in, const int* in_sizes, int n_in,
                              void* d_out, int out_size, void* d_ws, size_t ws_size,
                              hipStream_t stream) {
  const float* x    = (const float*)d_in[0];
  const float* ln1g = (const float*)d_in[1];
  const float* ln1b = (const float*)d_in[2];
  const float* wq   = (const float*)d_in[3];
  const float* wk   = (const float*)d_in[4];
  const float* wv   = (const float*)d_in[5];
  const float* wo   = (const float*)d_in[6];
  const float* bo   = (const float*)d_in[7];
  const float* ln2g = (const float*)d_in[8];
  const float* ln2b = (const float*)d_in[9];
  const float* wff1 = (const float*)d_in[10];
  const float* bff1 = (const float*)d_in[11];
  const float* wff2 = (const float*)d_in[12];
  const float* bff2 = (const float*)d_in[13];
  const float* wd   = (const float*)d_in[14];
  const float* bd   = (const float*)d_in[15];

  // d_out (64MB fp32) as scratch: first half xln (bf16 LN1(x)), second x2.
  bf16* xln = (bf16*)d_out;                           // 16384x1024 bf16
  bf16* x2  = (bf16*)d_out + (size_t)16384 * 1024;    // 16384x1024 bf16
  float* outf = (float*)d_out;

  char* wsp = (char*)d_ws;
  size_t off = 0;
  auto alloc = [&](size_t bytes) -> void* {
    void* p = wsp + off; off += (bytes + 255) & ~(size_t)255; return p;
  };
  bf16*   S1  = (bf16*)alloc((size_t)8 * 1024 * 1024);    // KV lo | q~ lo | wff1T
  bf16*   S2  = (bf16*)alloc((size_t)10 * 1024 * 1024);   // KV hi | q~ hi | WB
  bf16*   G   = (bf16*)alloc((size_t)10 * 1024 * 1024);   // ctx partials | CWT | [g|x2_R]
  bf16*   CTX = (bf16*)alloc((size_t)4 * 256 * 256 * 2);  // OB overlay (FFN)
  bf16*   W1  = (bf16*)alloc((size_t)1024 * 256 * 2);     // (spare)
  float2* st1 = (float2*)alloc((size_t)16384 * 8);
  float2* st2 = (float2*)alloc((size_t)16384 * 8);
  bf16*   KV   = S1;                           // [4b][512e][4096n] = 16MB (S1+S2)
  bf16*   W1kv = G + (size_t)9 * 512 * 1024;   // G bytes [9MB,10MB): [512][1024]
  bf16*   CTXT = S2 + (size_t)4 * 1024 * 1024; // S2 bytes [8MB,10MB): [4b][4h][256][256]
  bf16*   woT  = G + (size_t)4 * 1024 * 1024;  // G bytes [8MB,10MB): [1024][1024]
  bf16*   CWT  = G;                            // G bytes [0,8MB): [4b][1024c][1024hd]
  bf16*   wqT  = CTXT;                         // reuse after CWT built
  bf16*   QB   = S1;                           // q~ pair buffer [8192][1024] (16MB)
  bf16*   WB   = S2;                           // FFN: [1024][5120] = [WCD^T|wd^T]
  float*  OB   = (float*)CTX;                  // 4KB, FFN phase
  // total ws = 30,670,848 B — identical to the proven baseline footprint.

  const long SA  = (long)4096 * 1024;  // per-batch xln row stride (elements)
  const long PKV = (long)512 * 4096;   // per-batch KV [e][n] stride
  dim3 tb(32, 8);
  const bf16* nb = nullptr;

  // ---- LN1 stats + xln = bf16(LN1(x)) ----
  ln_stats_f32<<<16384, 256, 0, stream>>>(x, st1);
  ln_apply<<<8192, 256, 0, stream>>>(x, st1, ln1g, ln1b, xln);

  // ---- attention phase 1: per head, KV + context[d][e] ----
  for (int h = 0; h < 4; h++) {
    // KV = (xln @ [wk_h|wv_h])^T -> [4b][512e][4096n]; k rows then v rows.
    transpose_f2b<<<dim3(8, 32), tb, 0, stream>>>(wk + h * 256, W1kv, 1024, 1024);
    transpose_f2b<<<dim3(8, 32), tb, 0, stream>>>(wv + h * 256, W1kv + 256 * 1024, 1024, 1024);
    gemm_bt<1, 0, 0, 0><<<dim3(4, 32, 4), 256, 0, stream>>>(xln, W1kv, KV,
        1024, 1024, 1024, 4096, 2, 0, SA, 0, 0, 0, PKV,
        nullptr, nb, 0, nullptr, nullptr, nullptr);
    ksoftmaxKV<<<1024, 256, 0, stream>>>(KV);

    // ctx partials: G[kc][b][d][e] = sum_{n in kc} k~[d][n] * v[e][n]
    // (16 seq-chunks of 256 -> 256 blocks)
    gemm_bt<0, 0, 0, 0><<<dim3(2, 2, 64), 256, 0, stream>>>(KV, KV + (long)256 * 4096, G,
        256, 4096, 4096, 256, 4, PKV, 256, PKV, 256, 65536, 262144,
        nullptr, nb, 0, nullptr, nullptr, nullptr);
    reduce_ctx<<<1024, 256, 0, stream>>>(G, CTXT + h * 65536);
  }

  // ---- attention phase 1.5: CWT[b][c][(h,d)] = sum_e wo_h[e][c]*ctx_h[d][e] ----
  transpose_f2b<<<dim3(32, 32), tb, 0, stream>>>(wo, woT, 1024, 1024);
  gemm_bt<0, 0, 0, 0><<<dim3(2, 8, 16), 256, 0, stream>>>(woT, CTXT, CWT,
      256, 1024, 256, 1024, 2, 0, 256, 262144, 65536, 1048576, 256,
      nullptr, nb, 0, nullptr, nullptr, nullptr);
  transpose_f2b<<<dim3(32, 32), tb, 0, stream>>>(wq, wqT, 1024, 1024);  // CTXT dead

  // ---- attention phase 2: per batch-pair, q~ (all heads) then x2 ----
  for (int p = 0; p < 2; p++) {
    // q = xln_pair @ wq (all heads) -> QB [8192][1024]
    gemm_bt<0, 0, 0, 0><<<dim3(8, 64, 1), 256, 0, stream>>>(
        xln + (size_t)p * 8192 * 1024, wqT, QB,
        1024, 1024, 1024, 1024, 0, 0, 0, 0, 0, 0, 0,
        nullptr, nb, 0, nullptr, nullptr, nullptr);
    qsoftmax256<<<32768, 256, 0, stream>>>(QB);
    // x2_pair = x_pair + bo + q~ @ CWT[b]  (z = batch-in-pair)
    gemm_bt<0, 0, 0, 0, 1><<<dim3(8, 32, 2), 256, 0, stream>>>(
        QB, CWT + (size_t)p * 2 * 1048576, x2 + (size_t)p * 8192 * 1024,
        1024, 1024, 1024, 1024, 1, 0, SA, 0, 1048576, 0, SA,
        bo, (const bf16*)(x + (size_t)p * 8192 * 1024), 0,
        nullptr, nullptr, nullptr);
  }

  // ---- FFN + trailing dense: out = [g|x2_R] @ [WCD^T|wd^T]^T + OB ----
  ln_stats_b16<<<16384, 256, 0, stream>>>(x2, st2);
  transpose_f2b<<<dim3(128, 32), tb, 0, stream>>>(wff1, S1, 4096, 1024);  // S1 = wff1T
  // WB cols [4096:5120) = wd^T  (row stride 5120)
  transpose_f2b<<<dim3(32, 32), tb, 0, stream>>>(wd, WB + 4096, 1024, 5120);
  // WB cols [0:4096) = WCD^T = (wff2@wd)^T; B operand = wd^T slice of WB.
  gemm_bt<1, 1, 0, 0><<<dim3(8, 32, 1), 256, 0, stream>>>(wff2, WB + 4096, WB,
      1024, 1024, 5120, 5120, 0, 0, 0, 0, 0, 0, 0,
      nullptr, nb, 0, nullptr, nullptr, nullptr);
  // OB[n] = b_ff2 @ wd + b_d
  out_bias<<<1024, 256, 0, stream>>>(bff2, WB + 4096, 5120, bd, OB);

  for (int R = 0; R < 16; R++) {
    const bf16* xr = x2 + (size_t)R * 1024 * 1024;  // x2 rows (bf16)
    // G cols [4096:5120) = x2_R  (also rescues chunk 15 from its own out-write)
    copy_cols<<<1024, 128, 0, stream>>>(xr, G);
    // G cols [0:4096) = gelu(LN2(x2_R) @ wff1T + b1)
    gemm_bt<0, 0, 0, 0><<<dim3(32, 8, 1), 256, 0, stream>>>(xr, S1, G,
        1024, 1024, 1024, 5120, 2, 0, 0, 0, 0, 0, 0,
        bff1, nb, 1, st2 + R * 1024, ln2g, ln2b);
    // out_R = OB (seed); after gemm1(R) — chunk 15's out-write covers x2 rows
    // gemm1(15) reads.
    bias_bcast<<<1024, 256, 0, stream>>>(OB, outf + (size_t)R * 1024 * 1024);
    // out_R += [g|x2_R] @ WB^T  (split-K: z=4 slices of K=1280 -> 256 blocks)
    gemm_bt<0, 0, 1, 1><<<dim3(8, 8, 4), 256, 0, stream>>>(G, WB,
        outf + (size_t)R * 1024 * 1024,
        1280, 5120, 5120, 1024, 2, 0, 1280, 0, 1280, 0, 0,
        nullptr, nb, 0, nullptr, nullptr, nullptr);
  }
}